// Round 11
// baseline (271.467 us; speedup 1.0000x reference)
//
#include <hip/hip_runtime.h>

#define B_ 2
#define NQ_ 512
#define NC_ 2048
#define D_ 768
#define H_ 12
#define HD_ 64
#define FF_ 3072
#define RB_ 64

typedef unsigned short u16;
typedef __attribute__((ext_vector_type(4))) unsigned short u16x4;
typedef __attribute__((ext_vector_type(8))) short short8;
typedef __attribute__((ext_vector_type(4))) float f32x4;
typedef __attribute__((ext_vector_type(2))) float f32x2;

#define SCL2 0.18033688f   /* 0.125 * log2(e) */

__device__ __forceinline__ float bf2f(u16 u) {
    unsigned int i = ((unsigned int)u) << 16;
    float f; __builtin_memcpy(&f, &i, 4); return f;
}
__device__ __forceinline__ u16 f2bf(float f) {
    unsigned int i; __builtin_memcpy(&i, &f, 4);
    unsigned int r = i + 0x7FFFu + ((i >> 16) & 1u);
    return (u16)(r >> 16);
}
__device__ __forceinline__ float gelu_f(float x) {
    return 0.5f * x * (1.f + erff(x * 0.70710678118654752f));
}
__device__ __forceinline__ float wsum(float v) {
    v += __shfl_xor(v, 32); v += __shfl_xor(v, 16); v += __shfl_xor(v, 8);
    v += __shfl_xor(v, 4);  v += __shfl_xor(v, 2);  v += __shfl_xor(v, 1);
    return v;
}
__device__ __forceinline__ void gload_lds16(const void* g, void* l) {
    __builtin_amdgcn_global_load_lds((const __attribute__((address_space(1))) void*)g,
                                     (__attribute__((address_space(3))) void*)l, 16, 0, 0);
}
// ---- explicit packed fp32 (CDNA VOP3P; compiler scalarizes f32x2 otherwise) ----
__device__ __forceinline__ f32x2 pk_fma(f32x2 a, f32x2 b, f32x2 c) {
    f32x2 d;
    asm("v_pk_fma_f32 %0, %1, %2, %3" : "=v"(d) : "v"(a), "v"(b), "v"(c));
    return d;
}
__device__ __forceinline__ f32x2 pk_mul(f32x2 a, f32x2 b) {
    f32x2 d;
    asm("v_pk_mul_f32 %0, %1, %2" : "=v"(d) : "v"(a), "v"(b));
    return d;
}

// ---------------- weight transpose: (K,N) f32 -> (N,K) bf16 ----------------
__device__ __forceinline__ void wtrans_body(const float* __restrict__ in, u16* __restrict__ out,
                                            int K, int N, int bx, int by, int tid) {
    __shared__ float t[32][33];
    int n0 = bx * 32, k0 = by * 32;
    int tx = tid & 31, ty = tid >> 5;
#pragma unroll
    for (int r = 0; r < 4; ++r)
        t[ty + r * 8][tx] = in[(long)(k0 + ty + r * 8) * N + n0 + tx];
    __syncthreads();
#pragma unroll
    for (int r = 0; r < 4; ++r)
        out[(long)(n0 + ty + r * 8) * K + k0 + tx] = f2bf(t[tx][ty + r * 8]);
}

__global__ __launch_bounds__(256) void wtrans(const float* __restrict__ in, u16* __restrict__ out,
                                              int K, int N) {
    wtrans_body(in, out, K, N, blockIdx.x, blockIdx.y, threadIdx.x);
}

__global__ __launch_bounds__(256) void wtrans5(const float* i0, const float* i1, const float* i2,
                                               const float* i3, const float* i4,
                                               u16* o0, u16* o1, u16* o2, u16* o3, u16* o4) {
    const float* in; u16* out;
    switch (blockIdx.z) {
        case 0: in = i0; out = o0; break;
        case 1: in = i1; out = o1; break;
        case 2: in = i2; out = o2; break;
        case 3: in = i3; out = o3; break;
        default: in = i4; out = o4; break;
    }
    wtrans_body(in, out, 768, 768, blockIdx.x, blockIdx.y, threadIdx.x);
}

// ---------------- f32 -> bf16 convert (two tensors, y picks) ----------------
__global__ __launch_bounds__(256) void cvtk2(const float* __restrict__ inA, u16* __restrict__ outA,
                                             const float* __restrict__ inB, u16* __restrict__ outB, int n4) {
    int i = blockIdx.x * 256 + threadIdx.x;
    const float* in = blockIdx.y ? inB : inA;
    u16* out = blockIdx.y ? outB : outA;
    if (i < n4) {
        float4 v = ((const float4*)in)[i];
        u16x4 o; o.x = f2bf(v.x); o.y = f2bf(v.y); o.z = f2bf(v.z); o.w = f2bf(v.w);
        ((u16x4*)out)[i] = o;
    }
}

// ---------------- concat bk||bv into adjacent f32 buffer ----------------
__global__ __launch_bounds__(256) void catbias(const float* __restrict__ a, const float* __restrict__ b,
                                               float* __restrict__ o) {
    int i = blockIdx.x * 256 + threadIdx.x;
    if (i < 768) o[i] = a[i];
    else if (i < 1536) o[i] = b[i - 768];
}

// ---------------- LayerNorm: f32 in -> bf16 out, rows of D_=768 ----------------
__global__ __launch_bounds__(256) void ln_k(const float* __restrict__ x, const float* __restrict__ g,
                                            const float* __restrict__ bta, u16* __restrict__ out) {
    int row = blockIdx.x, t = threadIdx.x;
    const float* xr = x + (long)row * D_;
    float a0 = xr[t], a1 = xr[t + 256], a2 = xr[t + 512];
    float s = a0 + a1 + a2, s2 = a0 * a0 + a1 * a1 + a2 * a2;
    s = wsum(s); s2 = wsum(s2);
    __shared__ float rb[8];
    int lane = t & 63, wid = t >> 6;
    if (!lane) { rb[wid] = s; rb[wid + 4] = s2; }
    __syncthreads();
    float S = rb[0] + rb[1] + rb[2] + rb[3];
    float S2 = rb[4] + rb[5] + rb[6] + rb[7];
    float mean = S * (1.f / D_);
    float var = S2 * (1.f / D_) - mean * mean;
    float rstd = rsqrtf(var + 1e-5f);
    u16* orow = out + (long)row * D_;
    orow[t]       = f2bf((a0 - mean) * rstd * g[t]       + bta[t]);
    orow[t + 256] = f2bf((a1 - mean) * rstd * g[t + 256] + bta[t + 256]);
    orow[t + 512] = f2bf((a2 - mean) * rstd * g[t + 512] + bta[t + 512]);
}

// ---------------- relative-bias MLP v8: poly GELU via explicit v_pk_* ----------------
// gelu(x) = x * Phi(x), Phi = 0.5 + xc*(c1 + c3 u + c5 u^2 + c7 u^3 + c9 u^4),
// xc = clamp(x,-3,3), u = xc^2. Stores bias * log2(e).
__global__ __launch_bounds__(256) void bias_mlp8(
    const float* __restrict__ qcoord, const float* __restrict__ ccoord,
    const float* __restrict__ w1, const float* __restrict__ b1,
    const float* __restrict__ w2, const float* __restrict__ b2,
    u16* __restrict__ out) {
    __shared__ float s1[192];
    __shared__ float sw2[RB_ * H_];
    __shared__ float2 sc[256];
    __shared__ u16 sb[12 * 264];
    int tid = threadIdx.x;
    int b = blockIdx.z, q0 = blockIdx.y * 4, c0 = blockIdx.x * 256;
    if (tid < 64) { s1[tid] = w1[tid]; s1[64 + tid] = w1[64 + tid]; s1[128 + tid] = b1[tid]; }
    for (int i = tid; i < RB_ * H_; i += 256) sw2[i] = w2[i];
    sc[tid] = ((const float2*)ccoord)[b * NC_ + c0 + tid];
    __syncthreads();
    int lane = tid & 63, wid = tid >> 6;
    int h = lane & 15, g4 = lane >> 4;
    int j0 = g4 * 8;
    f32x2 wx[8], wy[8], bb[8];
#pragma unroll
    for (int p = 0; p < 4; ++p) {
        wx[p]     = (f32x2){s1[j0 + 2 * p],       s1[j0 + 2 * p + 1]};
        wy[p]     = (f32x2){s1[64 + j0 + 2 * p],  s1[64 + j0 + 2 * p + 1]};
        bb[p]     = (f32x2){s1[128 + j0 + 2 * p], s1[128 + j0 + 2 * p + 1]};
        wx[4 + p] = (f32x2){s1[32 + j0 + 2 * p],  s1[32 + j0 + 2 * p + 1]};
        wy[4 + p] = (f32x2){s1[96 + j0 + 2 * p],  s1[96 + j0 + 2 * p + 1]};
        bb[4 + p] = (f32x2){s1[160 + j0 + 2 * p], s1[160 + j0 + 2 * p + 1]};
    }
    short8 vb0, vb1;
#pragma unroll
    for (int u = 0; u < 8; ++u) {
        vb0[u] = (h < 12) ? (short)f2bf(sw2[(j0 + u) * H_ + h]) : (short)0;
        vb1[u] = (h < 12) ? (short)f2bf(sw2[(32 + j0 + u) * H_ + h]) : (short)0;
    }
    float qx[4], qy[4];
#pragma unroll
    for (int qq = 0; qq < 4; ++qq) {
        qx[qq] = qcoord[(b * NQ_ + q0 + qq) * 2];
        qy[qq] = qcoord[(b * NQ_ + q0 + qq) * 2 + 1];
    }
    float b2v = (h < 12) ? b2[h] : 0.f;
    // coeff broadcast pairs (VOP3P can't take literals)
    const f32x2 C9 = {2.3813e-5f, 2.3813e-5f};
    const f32x2 C7 = {-6.8939e-4f, -6.8939e-4f};
    const f32x2 C5 = {0.0086261f, 0.0086261f};
    const f32x2 C3 = {-0.064949f, -0.064949f};
    const f32x2 C1 = {0.39837f, 0.39837f};
    const f32x2 HHALF = {0.5f, 0.5f};
#pragma unroll 1
    for (int qq = 0; qq < 4; ++qq) {
        if (qq) __syncthreads();
#pragma unroll
        for (int it = 0; it < 4; ++it) {
            int ci = wid * 64 + it * 16 + h;
            float2 cc = sc[ci];
            float dx = qx[qq] - cc.x, dy = qy[qq] - cc.y;
            f32x2 dxp = {dx, dx}, dyp = {dy, dy};
            unsigned int pk[8];
#pragma unroll
            for (int p = 0; p < 8; ++p) {
                f32x2 pre = pk_fma(dxp, wx[p], bb[p]);
                pre = pk_fma(dyp, wy[p], pre);
                f32x2 xc = __builtin_elementwise_min(
                               __builtin_elementwise_max(pre, (f32x2)(-3.0f)), (f32x2)(3.0f));
                f32x2 u = pk_mul(xc, xc);
                f32x2 v = pk_fma(u, C9, C7);
                v = pk_fma(v, u, C5);
                v = pk_fma(v, u, C3);
                v = pk_fma(v, u, C1);
                f32x2 phi = pk_fma(xc, v, HHALF);
                f32x2 g = pk_mul(pre, phi);
                pk[p] = __builtin_amdgcn_perm(__builtin_bit_cast(unsigned int, g.y),
                                              __builtin_bit_cast(unsigned int, g.x), 0x07060302u);
            }
            uint4 d0 = {pk[0], pk[1], pk[2], pk[3]};
            uint4 d1 = {pk[4], pk[5], pk[6], pk[7]};
            short8 a0 = __builtin_bit_cast(short8, d0);
            short8 a1 = __builtin_bit_cast(short8, d1);
            f32x4 acc = {};
            acc = __builtin_amdgcn_mfma_f32_16x16x32_bf16(a0, vb0, acc, 0, 0, 0);
            acc = __builtin_amdgcn_mfma_f32_16x16x32_bf16(a1, vb1, acc, 0, 0, 0);
            if (h < 12) {
#pragma unroll
                for (int r = 0; r < 4; ++r) {
                    int loc = wid * 64 + it * 16 + g4 * 4 + r;
                    sb[h * 264 + loc] = f2bf((acc[r] + b2v) * 1.4426950f);
                }
            }
        }
        __syncthreads();
        for (int i = tid; i < 12 * 128; i += 256) {
            int row = i >> 7, cp = (i & 127) * 2;
            unsigned int pv = *(const unsigned int*)(sb + row * 264 + cp);
            *(unsigned int*)(out + (((long)(b * H_ + row) * NQ_ + q0 + qq) * NC_ + c0 + cp)) = pv;
        }
    }
}

// ---------------- bf16 strided transpose for V-slices ----------------
__global__ __launch_bounds__(256) void vtrans(const u16* __restrict__ in, u16* __restrict__ out,
                                              int NCt, int ldin, int bdiv, long sIb, long sIh) {
    __shared__ u16 t[32][33];
    int z = blockIdx.z, zb = z / bdiv, zh = z % bdiv;
    const u16* ib = in + zb * sIb + zh * sIh;
    int c0 = blockIdx.x * 32, d0 = blockIdx.y * 32;
    int tx = threadIdx.x & 31, ty = threadIdx.x >> 5;
#pragma unroll
    for (int r = 0; r < 4; ++r)
        t[ty + r * 8][tx] = ib[(long)(c0 + ty + r * 8) * ldin + d0 + tx];
    __syncthreads();
#pragma unroll
    for (int r = 0; r < 4; ++r)
        out[(long)z * 64 * NCt + (long)(d0 + ty + r * 8) * NCt + c0 + tx] = t[tx][ty + r * 8];
}

// ---------------- 1-wave flash attention (self-attn, no bias) ----------------
template <int NCT, bool HASBIAS>
__global__ __launch_bounds__(64) void fattn(
    const u16* __restrict__ Qb, const u16* __restrict__ Kb, const u16* __restrict__ Vtb,
    const u16* __restrict__ Bias, u16* __restrict__ Ob, int ldq, int ldk) {
    __shared__ u16 kl[2][128 * 64];
    __shared__ u16 vl[64 * 128];
    __shared__ u16 pl[16 * 128];
    const int lane = threadIdx.x;
    const int h16 = lane & 15, g4 = lane >> 4;
    const int hh = blockIdx.y, b = blockIdx.z, q0 = blockIdx.x * 16;
    const u16* Qrow = Qb + (long)(b * NQ_ + q0 + h16) * ldq + hh * 64;
    short8 qf0 = *(const short8*)(Qrow + g4 * 8);
    short8 qf1 = *(const short8*)(Qrow + 32 + g4 * 8);
    const u16* Kbase = Kb + (long)b * NCT * ldk + hh * 64;
    const u16* Vtbase = Vtb + (long)(b * H_ + hh) * 64 * NCT;

    auto stageK = [&](int buf, int c0) {
#pragma unroll
        for (int i = 0; i < 16; ++i) {
            int ch = i * 64 + lane;
            int row = ch >> 3, col2 = (ch & 7) * 16;
            int scol2 = col2 ^ ((row & 7) << 4);
            gload_lds16(Kbase + (long)(c0 + row) * ldk + (scol2 >> 1), &kl[buf][ch * 8]);
        }
    };
    auto stageV = [&](int c0) {
#pragma unroll
        for (int i = 0; i < 16; ++i) {
            int ch = i * 64 + lane;
            int row = ch >> 4, col2 = (ch & 15) * 16;
            int scol2 = col2 ^ ((row & 15) << 4);
            gload_lds16(Vtbase + (long)row * NCT + c0 + (scol2 >> 1), &vl[ch * 8]);
        }
    };

    float m0[4] = {-1e30f, -1e30f, -1e30f, -1e30f};
    float l0[4] = {0.f, 0.f, 0.f, 0.f};
    f32x4 oacc[4] = {};
    constexpr int T = NCT / 128;
    stageK(0, 0);
    for (int t = 0; t < T; ++t) {
        const int c0 = t * 128, cur = t & 1;
        asm volatile("s_waitcnt lgkmcnt(0)" ::: "memory");
        stageV(c0);
        if (t + 1 < T) stageK(cur ^ 1, c0 + 128);
        if (t + 1 < T) asm volatile("s_waitcnt vmcnt(32)" ::: "memory");
        else           asm volatile("s_waitcnt vmcnt(16)" ::: "memory");
        f32x4 sacc[8] = {};
        const u16* klc = kl[cur];
        __builtin_amdgcn_s_setprio(1);
#pragma unroll
        for (int n = 0; n < 8; ++n) {
            int row = n * 16 + h16, swz = (row & 7) << 4;
#pragma unroll
            for (int ks = 0; ks < 2; ++ks) {
                short8 kf = *(const short8*)((const char*)klc + row * 128 + ((ks * 64 + g4 * 16) ^ swz));
                sacc[n] = __builtin_amdgcn_mfma_f32_16x16x32_bf16(ks ? qf1 : qf0, kf, sacc[n], 0, 0, 0);
            }
        }
        __builtin_amdgcn_s_setprio(0);
        if (t + 1 < T) asm volatile("s_waitcnt vmcnt(16)" ::: "memory");
        else           asm volatile("s_waitcnt vmcnt(0)" ::: "memory");
        float cr[4];
#pragma unroll
        for (int r = 0; r < 4; ++r) {
            float mx = -1e30f;
#pragma unroll
            for (int n = 0; n < 8; ++n) {
                float s = sacc[n][r] * SCL2;
                sacc[n][r] = s; mx = fmaxf(mx, s);
            }
            mx = fmaxf(mx, __shfl_xor(mx, 1)); mx = fmaxf(mx, __shfl_xor(mx, 2));
            mx = fmaxf(mx, __shfl_xor(mx, 4)); mx = fmaxf(mx, __shfl_xor(mx, 8));
            float mn = fmaxf(m0[r], mx);
            cr[r] = __builtin_amdgcn_exp2f(m0[r] - mn); m0[r] = mn;
            float sum = 0.f;
#pragma unroll
            for (int n = 0; n < 8; ++n) {
                float p = __builtin_amdgcn_exp2f(sacc[n][r] - mn); sacc[n][r] = p; sum += p;
            }
            sum += __shfl_xor(sum, 1); sum += __shfl_xor(sum, 2);
            sum += __shfl_xor(sum, 4); sum += __shfl_xor(sum, 8);
            l0[r] = l0[r] * cr[r] + sum;
        }
#pragma unroll
        for (int n = 0; n < 8; ++n)
#pragma unroll
            for (int r = 0; r < 4; ++r) {
                int q = g4 * 4 + r, c = n * 16 + h16;
                *(u16*)((char*)pl + q * 256 + ((c * 2) ^ (q << 4))) =
                    (u16)(__builtin_bit_cast(unsigned int, sacc[n][r]) >> 16);
            }
#pragma unroll
        for (int d = 0; d < 4; ++d) {
            f32x4 o = oacc[d];
            o[0] *= cr[0]; o[1] *= cr[1]; o[2] *= cr[2]; o[3] *= cr[3];
            oacc[d] = o;
        }
        short8 pf[4];
#pragma unroll
        for (int ks = 0; ks < 4; ++ks)
            pf[ks] = *(const short8*)((const char*)pl + h16 * 256 + ((ks * 64 + g4 * 16) ^ (h16 << 4)));
        __builtin_amdgcn_s_setprio(1);
#pragma unroll
        for (int d = 0; d < 4; ++d) {
            int row = d * 16 + h16, swzv = (row & 15) << 4;
#pragma unroll
            for (int ks = 0; ks < 4; ++ks) {
                short8 vf = *(const short8*)((const char*)vl + row * 256 + ((ks * 64 + g4 * 16) ^ swzv));
                oacc[d] = __builtin_amdgcn_mfma_f32_16x16x32_bf16(pf[ks], vf, oacc[d], 0, 0, 0);
            }
        }
        __builtin_amdgcn_s_setprio(0);
    }
    float inv[4];
#pragma unroll
    for (int r = 0; r < 4; ++r) inv[r] = 1.f / l0[r];
    u16* Orow = Ob + (long)(b * NQ_ + q0) * D_ + hh * 64;
#pragma unroll
    for (int d = 0; d < 4; ++d)
#pragma unroll
        for (int r = 0; r < 4; ++r)
            Orow[(long)(g4 * 4 + r) * D_ + d * 16 + h16] = f2bf(oacc[d][r] * inv[r]);
}

// ---------------- 4-wave split-context flash attention with bias (KVBLK=64) ----------------
template <int T, int S>
__global__ __launch_bounds__(256) void fattn4(
    const u16* __restrict__ Qb, const u16* __restrict__ Kb, const u16* __restrict__ Vtb,
    const u16* __restrict__ Bias, float* __restrict__ Part,
    int ldq, int ldk, int ldv, int NCT) {
    __shared__ u16 kl[2][64 * 64];
    __shared__ u16 vl[64 * 64];
    __shared__ u16 bl[4][16 * 64];
    __shared__ u16 pl[4][16 * 64];
    const int tid = threadIdx.x, lane = tid & 63, wid = tid >> 6;
    const int h16 = lane & 15, g4 = lane >> 4;
    const int qb = blockIdx.x, hh = blockIdx.y;
    const int b = blockIdx.z / S, s = blockIdx.z % S;
    const int q0w = qb * 64 + wid * 16;
    const int cb = s * (T * 64);
    const u16* Qrow = Qb + (long)(b * NQ_ + q0w + h16) * ldq + hh * 64;
    short8 qf0 = *(const short8*)(Qrow + g4 * 8);
    short8 qf1 = *(const short8*)(Qrow + 32 + g4 * 8);
    const u16* Kbase = Kb + (long)b * NCT * ldk + hh * 64;
    const u16* Vtbase = Vtb + (long)(b * H_ + hh) * 64 * ldv;
    const u16* Bbase = Bias + ((long)(b * H_ + hh) * NQ_ + q0w) * NCT;
    u16* mypl = pl[wid];
    const u16* mybl = bl[wid];

    auto stageK = [&](int buf, int c0) {
#pragma unroll
        for (int i = 0; i < 2; ++i) {
            int ch = wid * 128 + i * 64 + lane;
            int row = ch >> 3, col2 = (ch & 7) * 16;
            int scol2 = col2 ^ ((row & 7) << 4);
            gload_lds16(Kbase + (long)(c0 + row) * ldk + (scol2 >> 1), &kl[buf][ch * 8]);
        }
    };
    auto stageV = [&](int c0) {
#pragma unroll
        for (int i = 0; i < 2; ++i) {
            int ch = wid * 128 + i * 64 + lane;
            int row = ch >> 3, col2 = (ch & 7) * 16;
            int scol2 = col2 ^ ((row & 7) << 4);
            gload_lds16(Vtbase + (long)row * ldv + c0 + (scol2 >> 1), &vl[ch * 8]);
        }
    };
    auto stageB = [&](int c0) {
#pragma unroll
        for (int i = 0; i < 2; ++i) {
            int ch = i * 64 + lane;
            int row = ch >> 3, c16 = ch & 7;
            int sc16 = c16 ^ (row & 7);
            gload_lds16(Bbase + (long)row * NCT + c0 + sc16 * 8, &bl[wid][ch * 8]);
        }
    };

    float m0[4] = {-1e30f, -1e30f, -1e30f, -1e30f};
    float l0[4] = {0.f, 0.f, 0.f, 0.f};
    f32x4 oacc[4] = {};
    stageK(0, cb);
    for (int t = 0; t < T; ++t) {
        const int c0 = cb + t * 64, cur = t & 1;
        if (t > 0) {
            asm volatile("s_waitcnt lgkmcnt(0)" ::: "memory");
            __builtin_amdgcn_sched_barrier(0);
            __builtin_amdgcn_s_barrier();
        }
        stageV(c0);
        stageB(c0);
        if (t + 1 < T) stageK(cur ^ 1, c0 + 64);
        if (t + 1 < T) asm volatile("s_waitcnt vmcnt(6)" ::: "memory");
        else           asm volatile("s_waitcnt vmcnt(4)" ::: "memory");
        __builtin_amdgcn_s_barrier();
        f32x4 sacc[4] = {};
        const u16* klc = kl[cur];
        __builtin_amdgcn_s_setprio(1);
#pragma unroll
        for (int n = 0; n < 4; ++n) {
            int row = n * 16 + h16, swz = (row & 7) << 4;
#pragma unroll
            for (int ks = 0; ks < 2; ++ks) {
                short8 kf = *(const short8*)((const char*)klc + row * 128 + ((ks * 64 + g4 * 16) ^ swz));
                sacc[n] = __builtin_amdgcn_mfma_f32_16x16x32_bf16(ks ? qf1 : qf0, kf, sacc[n], 0, 0, 0);
            }
        }
        __builtin_amdgcn_s_setprio(0);
        if (t + 1 < T) asm volatile("s_waitcnt vmcnt(2)" ::: "memory");
        else           asm volatile("s_waitcnt vmcnt(0)" ::: "memory");
        __builtin_amdgcn_s_barrier();
        float cr[4];
#pragma unroll
        for (int r = 0; r < 4; ++r) {
            int q = g4 * 4 + r;
            float mx = -1e30f;
#pragma unroll
            for (int n = 0; n < 4; ++n) {
                float bvv = bf2f(*(const u16*)((const char*)mybl + q * 128 +
                                 (((n * 16 + h16) * 2) ^ ((q & 7) << 4))));
                float sv = sacc[n][r] * SCL2 + bvv;
                sacc[n][r] = sv; mx = fmaxf(mx, sv);
            }
            mx = fmaxf(mx, __shfl_xor(mx, 1)); mx = fmaxf(mx, __shfl_xor(mx, 2));
            mx = fmaxf(mx, __shfl_xor(mx, 4)); mx = fmaxf(mx, __shfl_xor(mx, 8));
            float mn = fmaxf(m0[r], mx);
            cr[r] = __builtin_amdgcn_exp2f(m0[r] - mn); m0[r] = mn;
            float sum = 0.f;
#pragma unroll
            for (int n = 0; n < 4; ++n) {
                float p = __builtin_amdgcn_exp2f(sacc[n][r] - mn); sacc[n][r] = p; sum += p;
            }
            sum += __shfl_xor(sum, 1); sum += __shfl_xor(sum, 2);
            sum += __shfl_xor(sum, 4); sum += __shfl_xor(sum, 8);
            l0[r] = l0[r] * cr[r] + sum;
        }
#pragma unroll
        for (int n = 0; n < 4; ++n)
#pragma unroll
            for (int r = 0; r < 4; ++r) {
                int q = g4 * 4 + r, c = n * 16 + h16;
                *(u16*)((char*)mypl + q * 128 + ((c * 2) ^ ((q & 7) << 4))) =
                    (u16)(__builtin_bit_cast(unsigned int, sacc[n][r]) >> 16);
            }
#pragma unroll
        for (int d = 0; d < 4; ++d) {
            f32x4 o = oacc[d];
            o[0] *= cr[0]; o[1] *= cr[1]; o[2] *= cr[2]; o[3] *= cr[3];
            oacc[d] = o;
        }
        short8 pf[2];
#pragma unroll
        for (int ks = 0; ks < 2; ++ks)
            pf[ks] = *(const short8*)((const char*)mypl + h16 * 128 + ((ks * 64 + g4 * 16) ^ ((h16 & 7) << 4)));
        __builtin_amdgcn_s_setprio(1);
#pragma unroll
        for (int d = 0; d < 4; ++d) {
            int row = d * 16 + h16, swzv = (row & 7) << 4;
#pragma unroll
            for (int ks = 0; ks < 2; ++ks) {
                short8 vf = *(const short8*)((const char*)vl + row * 128 + ((ks * 64 + g4 * 16) ^ swzv));
                oacc[d] = __builtin_amdgcn_mfma_f32_16x16x32_bf16(pf[ks], vf, oacc[d], 0, 0, 0);
            }
        }
        __builtin_amdgcn_s_setprio(0);
    }
    float* P = Part + ((((long)(b * H_ + hh) * 32 + qb * 4 + wid) * S + s) * 1088);
#pragma unroll
    for (int d = 0; d < 4; ++d)
#pragma unroll
        for (int r = 0; r < 4; ++r)
            P[(g4 * 4 + r) * 64 + d * 16 + h16] = oacc[d][r];
    if (h16 == 0) {
#pragma unroll
        for (int r = 0; r < 4; ++r) {
            P[1024 + g4 * 4 + r] = m0[r];
            P[1056 + g4 * 4 + r] = l0[r];
        }
    }
}

// combine S=4 partials -> bf16 output rows (exp2 domain)
__global__ __launch_bounds__(64) void fcomb(const float* __restrict__ Part, u16* __restrict__ Ob) {
    int q16 = blockIdx.x, hh = blockIdx.y, b = blockIdx.z, lane = threadIdx.x;
    const float* base = Part + (((long)(b * H_ + hh) * 32 + q16) * 4) * 1088;
#pragma unroll 4
    for (int q = 0; q < 16; ++q) {
        float m0 = base[1024 + q],        m1 = base[1088 + 1024 + q];
        float m2 = base[2176 + 1024 + q], m3 = base[3264 + 1024 + q];
        float M = fmaxf(fmaxf(m0, m1), fmaxf(m2, m3));
        float w0 = __builtin_amdgcn_exp2f(m0 - M), w1 = __builtin_amdgcn_exp2f(m1 - M);
        float w2 = __builtin_amdgcn_exp2f(m2 - M), w3 = __builtin_amdgcn_exp2f(m3 - M);
        float L = w0 * base[1056 + q] + w1 * base[1088 + 1056 + q] +
                  w2 * base[2176 + 1056 + q] + w3 * base[3264 + 1056 + q];
        float o = w0 * base[q * 64 + lane] + w1 * base[1088 + q * 64 + lane] +
                  w2 * base[2176 + q * 64 + lane] + w3 * base[3264 + q * 64 + lane];
        Ob[(long)(b * NQ_ + q16 * 16 + q) * D_ + hh * 64 + lane] = f2bf(o * (1.f / L));
    }
}

// ---------------- batched bf16 GEMM, B supplied transposed (N,K) ----------------
enum { EP_BIAS = 0, EP_SCALE = 1, EP_RES = 3, EP_GELU = 4 };

template <int BM, int BN, int EPI>
__global__ __launch_bounds__(256) void gemm_bt(
    const u16* __restrict__ A, const u16* __restrict__ B, void* __restrict__ Cv,
    const float* __restrict__ bias, const float* __restrict__ res,
    int M, int N, int K, int lda, int ldb, int ldc,
    int bdiv, long sAb, long sAh, long sBb, long sBh, long sCb, long sCh,
    float scale, int biasz) {
    constexpr int BK = 64;
    __shared__ u16 lA[BM * BK];
    __shared__ u16 lB[BN * BK];
    const int z = blockIdx.z;
    const int zb = z / bdiv, zh = z % bdiv;
    const u16* Ab = A + zb * sAb + zh * sAh;
    const u16* Bb = B + zb * sBb + zh * sBh;
    const int bm = blockIdx.y * BM;
    const int bn = blockIdx.x * BN;
    const int tid = threadIdx.x;
    const int lane = tid & 63, wid = tid >> 6;
    const int wm = (wid >> 1) * (BM / 2);
    const int wn = (wid & 1) * (BN / 2);
    constexpr int FM = BM / 32, FN = BN / 32;
    f32x4 acc[FM][FN] = {};
    const int lrow = lane & 15, lk = (lane >> 4) * 8;

    for (int kb = 0; kb < K; kb += BK) {
#pragma unroll
        for (int i = 0; i < (BM * 8) / 256; ++i) {
            int ch = tid + i * 256;
            int r = ch >> 3, c = ch & 7;
            gload_lds16(Ab + (long)(bm + r) * lda + kb + c * 8, lA + ch * 8);
        }
#pragma unroll
        for (int i = 0; i < (BN * 8) / 256; ++i) {
            int ch = tid + i * 256;
            int r = ch >> 3, c = ch & 7;
            gload_lds16(Bb + (long)(bn + r) * ldb + kb + c * 8, lB + ch * 8);
        }
        __syncthreads();
#pragma unroll
        for (int ks = 0; ks < 2; ++ks) {
            short8 af[FM], bfr[FN];
#pragma unroll
            for (int i = 0; i < FM; ++i)
                af[i] = *(const short8*)(lA + (wm + i * 16 + lrow) * BK + ks * 32 + lk);
#pragma unroll
            for (int j = 0; j < FN; ++j)
                bfr[j] = *(const short8*)(lB + (wn + j * 16 + lrow) * BK + ks * 32 + lk);
#pragma unroll
            for (int i = 0; i < FM; ++i)
#pragma unroll
                for (int j = 0; j < FN; ++j)
                    acc[i][j] = __builtin_amdgcn_mfma_f32_16x16x32_bf16(af[i], bfr[j], acc[i][j], 0, 0, 0);
        }
        __syncthreads();
    }

    long coff = zb * sCb + zh * sCh;
#pragma unroll
    for (int i = 0; i < FM; ++i) {
#pragma unroll
        for (int j = 0; j < FN; ++j) {
#pragma unroll
            for (int r = 0; r < 4; ++r) {
                int row = bm + wm + i * 16 + (lane >> 4) * 4 + r;
                int col = bn + wn + j * 16 + (lane & 15);
                long idx = coff + (long)row * ldc + col;
                float v = acc[i][j][r];
                if (EPI == EP_SCALE) {
                    ((u16*)Cv)[idx] = f2bf(v * scale);
                } else if (EPI == EP_RES) {
                    float tt = v + (bias ? bias[col] : 0.f);
                    ((float*)Cv)[idx] = res[idx] + tt;
                } else if (EPI == EP_GELU) {
                    float tt = v + (bias ? bias[col] : 0.f);
                    ((u16*)Cv)[idx] = f2bf(gelu_f(tt));
                } else {
                    float tt = v + (bias ? bias[biasz * zb + col] : 0.f);
                    ((u16*)Cv)[idx] = f2bf(tt);
                }
            }
        }
    }
}

extern "C" void kernel_launch(void* const* d_in, const int* in_sizes, int n_in,
                              void* d_out, int out_size, void* d_ws, size_t ws_size,
                              hipStream_t stream) {
    const float* x_in   = (const float*)d_in[0];
    const float* ctx_k  = (const float*)d_in[1];
    const float* ctx_v  = (const float*)d_in[2];
    const float* qcoord = (const float*)d_in[3];
    const float* ccoord = (const float*)d_in[4];
    const float* sn_g   = (const float*)d_in[5];
    const float* sn_b   = (const float*)d_in[6];
    const float* wqkv   = (const float*)d_in[7];
    const float* bqkv   = (const float*)d_in[8];
    const float* wo_s   = (const float*)d_in[9];
    const float* bo_s   = (const float*)d_in[10];
    const float* cn_g   = (const float*)d_in[11];
    const float* cn_b   = (const float*)d_in[12];
    const float* wq     = (const float*)d_in[13];
    const float* bq     = (const float*)d_in[14];
    const float* wk     = (const float*)d_in[15];
    const float* bk     = (const float*)d_in[16];
    const float* wv     = (const float*)d_in[17];
    const float* bv     = (const float*)d_in[18];
    const float* wo_c   = (const float*)d_in[19];
    const float* bo_c   = (const float*)d_in[20];
    const float* rb_w1  = (const float*)d_in[21];
    const float* rb_b1  = (const float*)d_in[22];
    const float* rb_w2  = (const float*)d_in[23];
    const float* rb_b2  = (const float*)d_in[24];
    const float* fn_g   = (const float*)d_in[25];
    const float* fn_b   = (const float*)d_in[26];
    const float* fw1    = (const float*)d_in[27];
    const float* fb1    = (const float*)d_in[28];
    const float* fw2    = (const float*)d_in[29];
    const float* fb2    = (const float*)d_in[30];

    char* ws = (char*)d_ws;
    size_t off = 0;
    auto alloc = [&](size_t bytes) -> void* {
        void* p = ws + off; off += (bytes + 255) & ~(size_t)255; return p;
    };
    u16* wT_qkv = (u16*)alloc((size_t)2304 * 768 * 2);
    u16* wT_os  = (u16*)alloc((size_t)768 * 768 * 2);
    u16* wT_q   = (u16*)alloc((size_t)768 * 768 * 2);
    u16* wT_k   = (u16*)alloc((size_t)768 * 768 * 2);   // adjacent to wT_v (sBb)
    u16* wT_v   = (u16*)alloc((size_t)768 * 768 * 2);
    u16* wT_oc  = (u16*)alloc((size_t)768 * 768 * 2);
    u16* wT_f1  = (u16*)alloc((size_t)3072 * 768 * 2);
    u16* wT_f2  = (u16*)alloc((size_t)768 * 3072 * 2);
    u16* ckb    = (u16*)alloc((size_t)B_ * NC_ * D_ * 2);  // adjacent to cvb (sAb)
    u16* cvb    = (u16*)alloc((size_t)B_ * NC_ * D_ * 2);
    u16* xln    = (u16*)alloc((size_t)1024 * 768 * 2);
    u16* qkv    = (u16*)alloc((size_t)1024 * 2304 * 2);
    u16* vts    = (u16*)alloc((size_t)24 * 64 * 512 * 2);
    u16* oatt   = (u16*)alloc((size_t)1024 * 768 * 2);
    float* x1   = (float*)alloc((size_t)1024 * 768 * 4);
    u16* xln2   = (u16*)alloc((size_t)1024 * 768 * 2);
    u16* qc     = (u16*)alloc((size_t)1024 * 768 * 2);
    u16* kc     = (u16*)alloc((size_t)4096 * 768 * 2);  // adjacent to vc (sCb)
    u16* vc     = (u16*)alloc((size_t)4096 * 768 * 2);
    u16* clog   = (u16*)alloc((size_t)24 * 512 * 2048 * 2);
    u16* vtc    = (u16*)alloc((size_t)24 * 64 * 2048 * 2);
    u16* oc2    = (u16*)alloc((size_t)1024 * 768 * 2);
    float* x2   = (float*)alloc((size_t)1024 * 768 * 4);
    u16* xln3   = (u16*)alloc((size_t)1024 * 768 * 2);
    u16* ffh    = (u16*)alloc((size_t)1024 * 3072 * 2);
    float* part = (float*)alloc((size_t)2 * H_ * 32 * 4 * 1088 * 4);
    float* bkv  = (float*)alloc((size_t)1536 * 4);
    (void)ws_size; (void)in_sizes; (void)n_in; (void)out_size;

    // weights -> (N,K) bf16
    wtrans<<<dim3(2304 / 32, 768 / 32), 256, 0, stream>>>(wqkv, wT_qkv, 768, 2304);
    wtrans5<<<dim3(24, 24, 5), 256, 0, stream>>>(wo_s, wq, wk, wv, wo_c,
                                                 wT_os, wT_q, wT_k, wT_v, wT_oc);
    wtrans<<<dim3(3072 / 32, 768 / 32), 256, 0, stream>>>(fw1, wT_f1, 768, 3072);
    wtrans<<<dim3(768 / 32, 3072 / 32), 256, 0, stream>>>(fw2, wT_f2, 3072, 768);
    cvtk2<<<dim3(B_ * NC_ * D_ / 4 / 256, 2), 256, 0, stream>>>(ctx_k, ckb, ctx_v, cvb, B_ * NC_ * D_ / 4);
    catbias<<<6, 256, 0, stream>>>(bk, bv, bkv);

    // ---- self attention ----
    ln_k<<<1024, 256, 0, stream>>>(x_in, sn_g, sn_b, xln);
    gemm_bt<64, 128, EP_BIAS><<<dim3(2304 / 128, 1024 / 64, 1), 256, 0, stream>>>(
        xln, wT_qkv, qkv, bqkv, nullptr, 1024, 2304, 768, 768, 768, 2304,
        1, 0, 0, 0, 0, 0, 0, 1.f, 0);
    bias_mlp8<<<dim3(NC_ / 256, NQ_ / 4, B_), 256, 0, stream>>>(qcoord, ccoord, rb_w1, rb_b1, rb_w2, rb_b2, clog);
    vtrans<<<dim3(512 / 32, 2, 24), 256, 0, stream>>>(qkv + 1536, vts, 512, 2304, 12, (long)512 * 2304, 64);
    fattn<512, false><<<dim3(NQ_ / 16, H_, B_), 64, 0, stream>>>(
        qkv, qkv + 768, vts, nullptr, oatt, 2304, 2304);
    gemm_bt<32, 64, EP_RES><<<dim3(768 / 64, 1024 / 32, 1), 256, 0, stream>>>(
        oatt, wT_os, x1, bo_s, x_in, 1024, 768, 768, 768, 768, 768,
        1, 0, 0, 0, 0, 0, 0, 1.f, 0);

    // ---- cross attention ----
    ln_k<<<1024, 256, 0, stream>>>(x1, cn_g, cn_b, xln2);
    gemm_bt<32, 64, EP_BIAS><<<dim3(768 / 64, 1024 / 32, 1), 256, 0, stream>>>(
        xln2, wT_q, qc, bq, nullptr, 1024, 768, 768, 768, 768, 768,
        1, 0, 0, 0, 0, 0, 0, 1.f, 0);
    // merged K-proj (z=0) + V-proj (z=1): adjacent A/B/C/bias buffers
    gemm_bt<64, 128, EP_BIAS><<<dim3(768 / 128, 4096 / 64, 2), 256, 0, stream>>>(
        ckb, wT_k, kc, bkv, nullptr, 4096, 768, 768, 768, 768, 768,
        1, (long)B_ * NC_ * D_, 0, (long)768 * 768, 0, (long)4096 * 768, 0, 1.f, 768);
    vtrans<<<dim3(2048 / 32, 2, 24), 256, 0, stream>>>(vc, vtc, 2048, 768, 12, (long)2048 * 768, 64);
    fattn4<8, 4><<<dim3(8, H_, B_ * 4), 256, 0, stream>>>(
        qc, kc, vtc, clog, part, 768, 768, 2048, 2048);
    fcomb<<<dim3(32, H_, B_), 64, 0, stream>>>(part, oc2);
    gemm_bt<32, 64, EP_RES><<<dim3(768 / 64, 1024 / 32, 1), 256, 0, stream>>>(
        oc2, wT_oc, x2, bo_c, x1, 1024, 768, 768, 768, 768, 768,
        1, 0, 0, 0, 0, 0, 0, 1.f, 0);

    // ---- FFN ----
    ln_k<<<1024, 256, 0, stream>>>(x2, fn_g, fn_b, xln3);
    gemm_bt<64, 128, EP_GELU><<<dim3(3072 / 128, 1024 / 64, 1), 256, 0, stream>>>(
        xln3, wT_f1, ffh, fb1, nullptr, 1024, 3072, 768, 768, 768, 3072,
        1, 0, 0, 0, 0, 0, 0, 1.f, 0);
    gemm_bt<32, 64, EP_RES><<<dim3(768 / 64, 1024 / 32, 1), 256, 0, stream>>>(
        ffh, wT_f2, (float*)d_out, fb2, x2, 1024, 768, 3072, 3072, 3072, 768,
        1, 0, 0, 0, 0, 0, 0, 1.f, 0);
}

// Round 12
// 241.982 us; speedup vs baseline: 1.1218x; 1.1218x over previous
//
#include <hip/hip_runtime.h>

#define B_ 2
#define NQ_ 512
#define NC_ 2048
#define D_ 768
#define H_ 12
#define HD_ 64
#define FF_ 3072
#define RB_ 64

typedef unsigned short u16;
typedef __attribute__((ext_vector_type(4))) unsigned short u16x4;
typedef __attribute__((ext_vector_type(8))) short short8;
typedef __attribute__((ext_vector_type(4))) float f32x4;
typedef __attribute__((ext_vector_type(2))) float f32x2;

#define SCL2 0.18033688f   /* 0.125 * log2(e) */

__device__ __forceinline__ float bf2f(u16 u) {
    unsigned int i = ((unsigned int)u) << 16;
    float f; __builtin_memcpy(&f, &i, 4); return f;
}
__device__ __forceinline__ u16 f2bf(float f) {
    unsigned int i; __builtin_memcpy(&i, &f, 4);
    unsigned int r = i + 0x7FFFu + ((i >> 16) & 1u);
    return (u16)(r >> 16);
}
__device__ __forceinline__ float gelu_f(float x) {
    return 0.5f * x * (1.f + erff(x * 0.70710678118654752f));
}
__device__ __forceinline__ float wsum(float v) {
    v += __shfl_xor(v, 32); v += __shfl_xor(v, 16); v += __shfl_xor(v, 8);
    v += __shfl_xor(v, 4);  v += __shfl_xor(v, 2);  v += __shfl_xor(v, 1);
    return v;
}
__device__ __forceinline__ void gload_lds16(const void* g, void* l) {
    __builtin_amdgcn_global_load_lds((const __attribute__((address_space(1))) void*)g,
                                     (__attribute__((address_space(3))) void*)l, 16, 0, 0);
}

// ---------------- weight transpose body: (K,N) f32 -> (N,K) bf16 ----------------
__device__ __forceinline__ void wtrans_body(const float* __restrict__ in, u16* __restrict__ out,
                                            int K, int N, int bx, int by, int tid) {
    __shared__ float t[32][33];
    int n0 = bx * 32, k0 = by * 32;
    int tx = tid & 31, ty = tid >> 5;
#pragma unroll
    for (int r = 0; r < 4; ++r)
        t[ty + r * 8][tx] = in[(long)(k0 + ty + r * 8) * N + n0 + tx];
    __syncthreads();
#pragma unroll
    for (int r = 0; r < 4; ++r)
        out[(long)(n0 + ty + r * 8) * K + k0 + tx] = f2bf(t[tx][ty + r * 8]);
}

// ---------------- merged prep: all weight transposes + ctx converts + bias concat ----------------
__global__ __launch_bounds__(256) void prep(
    const float* wqkv, u16* wT_qkv,
    const float* wo_s, const float* wq, const float* wk, const float* wv, const float* wo_c,
    u16* wT_os, u16* wT_q, u16* wT_k, u16* wT_v, u16* wT_oc,
    const float* fw1, u16* wT_f1, const float* fw2, u16* wT_f2,
    const float* ctx_k, u16* ckb, const float* ctx_v, u16* cvb,
    const float* bk, const float* bv, float* bkv) {
    int i = blockIdx.x, tid = threadIdx.x;
    if (i < 1728) { wtrans_body(wqkv, wT_qkv, 768, 2304, i % 72, i / 72, tid); return; }
    i -= 1728;
    if (i < 2880) {
        int z = i / 576, rem = i % 576;
        const float* in; u16* out;
        switch (z) {
            case 0: in = wo_s; out = wT_os; break;
            case 1: in = wq;   out = wT_q;  break;
            case 2: in = wk;   out = wT_k;  break;
            case 3: in = wv;   out = wT_v;  break;
            default: in = wo_c; out = wT_oc; break;
        }
        wtrans_body(in, out, 768, 768, rem % 24, rem / 24, tid);
        return;
    }
    i -= 2880;
    if (i < 2304) { wtrans_body(fw1, wT_f1, 768, 3072, i % 96, i / 96, tid); return; }
    i -= 2304;
    if (i < 2304) { wtrans_body(fw2, wT_f2, 3072, 768, i % 24, i / 24, tid); return; }
    i -= 2304;
    if (i < 6144) {
        int y = i / 3072;
        int ii = (i % 3072) * 256 + tid;
        const float* in = y ? ctx_v : ctx_k;
        u16* out = y ? cvb : ckb;
        float4 v = ((const float4*)in)[ii];
        u16x4 o; o.x = f2bf(v.x); o.y = f2bf(v.y); o.z = f2bf(v.z); o.w = f2bf(v.w);
        ((u16x4*)out)[ii] = o;
        return;
    }
    i -= 6144;
    {
        int j = i * 256 + tid;
        if (j < 768) bkv[j] = bk[j];
        else if (j < 1536) bkv[j] = bv[j - 768];
    }
}

// ---------------- LayerNorm: f32 in -> bf16 out, rows of D_=768 ----------------
__global__ __launch_bounds__(256) void ln_k(const float* __restrict__ x, const float* __restrict__ g,
                                            const float* __restrict__ bta, u16* __restrict__ out) {
    int row = blockIdx.x, t = threadIdx.x;
    const float* xr = x + (long)row * D_;
    float a0 = xr[t], a1 = xr[t + 256], a2 = xr[t + 512];
    float s = a0 + a1 + a2, s2 = a0 * a0 + a1 * a1 + a2 * a2;
    s = wsum(s); s2 = wsum(s2);
    __shared__ float rb[8];
    int lane = t & 63, wid = t >> 6;
    if (!lane) { rb[wid] = s; rb[wid + 4] = s2; }
    __syncthreads();
    float S = rb[0] + rb[1] + rb[2] + rb[3];
    float S2 = rb[4] + rb[5] + rb[6] + rb[7];
    float mean = S * (1.f / D_);
    float var = S2 * (1.f / D_) - mean * mean;
    float rstd = rsqrtf(var + 1e-5f);
    u16* orow = out + (long)row * D_;
    orow[t]       = f2bf((a0 - mean) * rstd * g[t]       + bta[t]);
    orow[t + 256] = f2bf((a1 - mean) * rstd * g[t + 256] + bta[t + 256]);
    orow[t + 512] = f2bf((a2 - mean) * rstd * g[t + 512] + bta[t + 512]);
}

// ---------------- bias MLP body (v7 polynomial GELU, scalar codegen) ----------------
// smem layout: s1 f32[192] @0 | sw2 f32[768] @768B | sc float2[256] @3840B | sb u16[12*264] @5888B
#define BIAS_SMEM_BYTES (5888 + 12 * 264 * 2)
__device__ __forceinline__ void bias_body(char* smem,
    const float* __restrict__ qcoord, const float* __restrict__ ccoord,
    const float* __restrict__ w1, const float* __restrict__ b1,
    const float* __restrict__ w2, const float* __restrict__ b2,
    u16* __restrict__ out, int cx, int q4, int b, int tid) {
    float* s1 = (float*)smem;
    float* sw2 = (float*)(smem + 768);
    float2* sc = (float2*)(smem + 3840);
    u16* sb = (u16*)(smem + 5888);
    int q0 = q4 * 4, c0 = cx * 256;
    if (tid < 64) { s1[tid] = w1[tid]; s1[64 + tid] = w1[64 + tid]; s1[128 + tid] = b1[tid]; }
    for (int i = tid; i < RB_ * H_; i += 256) sw2[i] = w2[i];
    sc[tid] = ((const float2*)ccoord)[b * NC_ + c0 + tid];
    __syncthreads();
    int lane = tid & 63, wid = tid >> 6;
    int h = lane & 15, g4 = lane >> 4;
    int j0 = g4 * 8;
    f32x2 wx[8], wy[8], bb[8];
#pragma unroll
    for (int p = 0; p < 4; ++p) {
        wx[p]     = (f32x2){s1[j0 + 2 * p],       s1[j0 + 2 * p + 1]};
        wy[p]     = (f32x2){s1[64 + j0 + 2 * p],  s1[64 + j0 + 2 * p + 1]};
        bb[p]     = (f32x2){s1[128 + j0 + 2 * p], s1[128 + j0 + 2 * p + 1]};
        wx[4 + p] = (f32x2){s1[32 + j0 + 2 * p],  s1[32 + j0 + 2 * p + 1]};
        wy[4 + p] = (f32x2){s1[96 + j0 + 2 * p],  s1[96 + j0 + 2 * p + 1]};
        bb[4 + p] = (f32x2){s1[160 + j0 + 2 * p], s1[160 + j0 + 2 * p + 1]};
    }
    short8 vb0, vb1;
#pragma unroll
    for (int u = 0; u < 8; ++u) {
        vb0[u] = (h < 12) ? (short)f2bf(sw2[(j0 + u) * H_ + h]) : (short)0;
        vb1[u] = (h < 12) ? (short)f2bf(sw2[(32 + j0 + u) * H_ + h]) : (short)0;
    }
    float qx[4], qy[4];
#pragma unroll
    for (int qq = 0; qq < 4; ++qq) {
        qx[qq] = qcoord[(b * NQ_ + q0 + qq) * 2];
        qy[qq] = qcoord[(b * NQ_ + q0 + qq) * 2 + 1];
    }
    float b2v = (h < 12) ? b2[h] : 0.f;
#pragma unroll 1
    for (int qq = 0; qq < 4; ++qq) {
        if (qq) __syncthreads();
#pragma unroll
        for (int it = 0; it < 4; ++it) {
            int ci = wid * 64 + it * 16 + h;
            float2 cc = sc[ci];
            float dx = qx[qq] - cc.x, dy = qy[qq] - cc.y;
            unsigned int pk[8];
#pragma unroll
            for (int p = 0; p < 8; ++p) {
                f32x2 pre = dx * wx[p] + bb[p];
                pre = dy * wy[p] + pre;
                f32x2 xc = __builtin_elementwise_min(
                               __builtin_elementwise_max(pre, (f32x2)(-3.0f)), (f32x2)(3.0f));
                f32x2 u = xc * xc;
                f32x2 v = u * 2.3813e-5f + (-6.8939e-4f);
                v = v * u + 0.0086261f;
                v = v * u + (-0.064949f);
                v = v * u + 0.39837f;
                f32x2 phi = xc * v + 0.5f;
                f32x2 g = pre * phi;
                pk[p] = __builtin_amdgcn_perm(__builtin_bit_cast(unsigned int, g.y),
                                              __builtin_bit_cast(unsigned int, g.x), 0x07060302u);
            }
            uint4 d0 = {pk[0], pk[1], pk[2], pk[3]};
            uint4 d1 = {pk[4], pk[5], pk[6], pk[7]};
            short8 a0 = __builtin_bit_cast(short8, d0);
            short8 a1 = __builtin_bit_cast(short8, d1);
            f32x4 acc = {};
            acc = __builtin_amdgcn_mfma_f32_16x16x32_bf16(a0, vb0, acc, 0, 0, 0);
            acc = __builtin_amdgcn_mfma_f32_16x16x32_bf16(a1, vb1, acc, 0, 0, 0);
            if (h < 12) {
#pragma unroll
                for (int r = 0; r < 4; ++r) {
                    int loc = wid * 64 + it * 16 + g4 * 4 + r;
                    sb[h * 264 + loc] = f2bf((acc[r] + b2v) * 1.4426950f);
                }
            }
        }
        __syncthreads();
        for (int i = tid; i < 12 * 128; i += 256) {
            int row = i >> 7, cp = (i & 127) * 2;
            unsigned int pv = *(const unsigned int*)(sb + row * 264 + cp);
            *(unsigned int*)(out + (((long)(b * H_ + row) * NQ_ + q0 + qq) * NC_ + c0 + cp)) = pv;
        }
    }
}

// ---------------- bf16 strided transpose for V-slices ----------------
__global__ __launch_bounds__(256) void vtrans(const u16* __restrict__ in, u16* __restrict__ out,
                                              int NCt, int ldin, int bdiv, long sIb, long sIh) {
    __shared__ u16 t[32][33];
    int z = blockIdx.z, zb = z / bdiv, zh = z % bdiv;
    const u16* ib = in + zb * sIb + zh * sIh;
    int c0 = blockIdx.x * 32, d0 = blockIdx.y * 32;
    int tx = threadIdx.x & 31, ty = threadIdx.x >> 5;
#pragma unroll
    for (int r = 0; r < 4; ++r)
        t[ty + r * 8][tx] = ib[(long)(c0 + ty + r * 8) * ldin + d0 + tx];
    __syncthreads();
#pragma unroll
    for (int r = 0; r < 4; ++r)
        out[(long)z * 64 * NCt + (long)(d0 + ty + r * 8) * NCt + c0 + tx] = t[tx][ty + r * 8];
}

// ---------------- 1-wave flash attention (self-attn, no bias) ----------------
template <int NCT, bool HASBIAS>
__global__ __launch_bounds__(64) void fattn(
    const u16* __restrict__ Qb, const u16* __restrict__ Kb, const u16* __restrict__ Vtb,
    const u16* __restrict__ Bias, u16* __restrict__ Ob, int ldq, int ldk) {
    __shared__ u16 kl[2][128 * 64];
    __shared__ u16 vl[64 * 128];
    __shared__ u16 pl[16 * 128];
    const int lane = threadIdx.x;
    const int h16 = lane & 15, g4 = lane >> 4;
    const int hh = blockIdx.y, b = blockIdx.z, q0 = blockIdx.x * 16;
    const u16* Qrow = Qb + (long)(b * NQ_ + q0 + h16) * ldq + hh * 64;
    short8 qf0 = *(const short8*)(Qrow + g4 * 8);
    short8 qf1 = *(const short8*)(Qrow + 32 + g4 * 8);
    const u16* Kbase = Kb + (long)b * NCT * ldk + hh * 64;
    const u16* Vtbase = Vtb + (long)(b * H_ + hh) * 64 * NCT;

    auto stageK = [&](int buf, int c0) {
#pragma unroll
        for (int i = 0; i < 16; ++i) {
            int ch = i * 64 + lane;
            int row = ch >> 3, col2 = (ch & 7) * 16;
            int scol2 = col2 ^ ((row & 7) << 4);
            gload_lds16(Kbase + (long)(c0 + row) * ldk + (scol2 >> 1), &kl[buf][ch * 8]);
        }
    };
    auto stageV = [&](int c0) {
#pragma unroll
        for (int i = 0; i < 16; ++i) {
            int ch = i * 64 + lane;
            int row = ch >> 4, col2 = (ch & 15) * 16;
            int scol2 = col2 ^ ((row & 15) << 4);
            gload_lds16(Vtbase + (long)row * NCT + c0 + (scol2 >> 1), &vl[ch * 8]);
        }
    };

    float m0[4] = {-1e30f, -1e30f, -1e30f, -1e30f};
    float l0[4] = {0.f, 0.f, 0.f, 0.f};
    f32x4 oacc[4] = {};
    constexpr int T = NCT / 128;
    stageK(0, 0);
    for (int t = 0; t < T; ++t) {
        const int c0 = t * 128, cur = t & 1;
        asm volatile("s_waitcnt lgkmcnt(0)" ::: "memory");
        stageV(c0);
        if (t + 1 < T) stageK(cur ^ 1, c0 + 128);
        if (t + 1 < T) asm volatile("s_waitcnt vmcnt(32)" ::: "memory");
        else           asm volatile("s_waitcnt vmcnt(16)" ::: "memory");
        f32x4 sacc[8] = {};
        const u16* klc = kl[cur];
        __builtin_amdgcn_s_setprio(1);
#pragma unroll
        for (int n = 0; n < 8; ++n) {
            int row = n * 16 + h16, swz = (row & 7) << 4;
#pragma unroll
            for (int ks = 0; ks < 2; ++ks) {
                short8 kf = *(const short8*)((const char*)klc + row * 128 + ((ks * 64 + g4 * 16) ^ swz));
                sacc[n] = __builtin_amdgcn_mfma_f32_16x16x32_bf16(ks ? qf1 : qf0, kf, sacc[n], 0, 0, 0);
            }
        }
        __builtin_amdgcn_s_setprio(0);
        if (t + 1 < T) asm volatile("s_waitcnt vmcnt(16)" ::: "memory");
        else           asm volatile("s_waitcnt vmcnt(0)" ::: "memory");
        float cr[4];
#pragma unroll
        for (int r = 0; r < 4; ++r) {
            float mx = -1e30f;
#pragma unroll
            for (int n = 0; n < 8; ++n) {
                float s = sacc[n][r] * SCL2;
                sacc[n][r] = s; mx = fmaxf(mx, s);
            }
            mx = fmaxf(mx, __shfl_xor(mx, 1)); mx = fmaxf(mx, __shfl_xor(mx, 2));
            mx = fmaxf(mx, __shfl_xor(mx, 4)); mx = fmaxf(mx, __shfl_xor(mx, 8));
            float mn = fmaxf(m0[r], mx);
            cr[r] = __builtin_amdgcn_exp2f(m0[r] - mn); m0[r] = mn;
            float sum = 0.f;
#pragma unroll
            for (int n = 0; n < 8; ++n) {
                float p = __builtin_amdgcn_exp2f(sacc[n][r] - mn); sacc[n][r] = p; sum += p;
            }
            sum += __shfl_xor(sum, 1); sum += __shfl_xor(sum, 2);
            sum += __shfl_xor(sum, 4); sum += __shfl_xor(sum, 8);
            l0[r] = l0[r] * cr[r] + sum;
        }
#pragma unroll
        for (int n = 0; n < 8; ++n)
#pragma unroll
            for (int r = 0; r < 4; ++r) {
                int q = g4 * 4 + r, c = n * 16 + h16;
                *(u16*)((char*)pl + q * 256 + ((c * 2) ^ (q << 4))) =
                    (u16)(__builtin_bit_cast(unsigned int, sacc[n][r]) >> 16);
            }
#pragma unroll
        for (int d = 0; d < 4; ++d) {
            f32x4 o = oacc[d];
            o[0] *= cr[0]; o[1] *= cr[1]; o[2] *= cr[2]; o[3] *= cr[3];
            oacc[d] = o;
        }
        short8 pf[4];
#pragma unroll
        for (int ks = 0; ks < 4; ++ks)
            pf[ks] = *(const short8*)((const char*)pl + h16 * 256 + ((ks * 64 + g4 * 16) ^ (h16 << 4)));
        __builtin_amdgcn_s_setprio(1);
#pragma unroll
        for (int d = 0; d < 4; ++d) {
            int row = d * 16 + h16, swzv = (row & 15) << 4;
#pragma unroll
            for (int ks = 0; ks < 4; ++ks) {
                short8 vf = *(const short8*)((const char*)vl + row * 256 + ((ks * 64 + g4 * 16) ^ swzv));
                oacc[d] = __builtin_amdgcn_mfma_f32_16x16x32_bf16(pf[ks], vf, oacc[d], 0, 0, 0);
            }
        }
        __builtin_amdgcn_s_setprio(0);
    }
    float inv[4];
#pragma unroll
    for (int r = 0; r < 4; ++r) inv[r] = 1.f / l0[r];
    u16* Orow = Ob + (long)(b * NQ_ + q0) * D_ + hh * 64;
#pragma unroll
    for (int d = 0; d < 4; ++d)
#pragma unroll
        for (int r = 0; r < 4; ++r)
            Orow[(long)(g4 * 4 + r) * D_ + d * 16 + h16] = f2bf(oacc[d][r] * inv[r]);
}

// ---------------- 4-wave split-context flash attention with bias (KVBLK=64) ----------------
template <int T, int S>
__global__ __launch_bounds__(256) void fattn4(
    const u16* __restrict__ Qb, const u16* __restrict__ Kb, const u16* __restrict__ Vtb,
    const u16* __restrict__ Bias, float* __restrict__ Part,
    int ldq, int ldk, int ldv, int NCT) {
    __shared__ u16 kl[2][64 * 64];
    __shared__ u16 vl[64 * 64];
    __shared__ u16 bl[4][16 * 64];
    __shared__ u16 pl[4][16 * 64];
    const int tid = threadIdx.x, lane = tid & 63, wid = tid >> 6;
    const int h16 = lane & 15, g4 = lane >> 4;
    const int qb = blockIdx.x, hh = blockIdx.y;
    const int b = blockIdx.z / S, s = blockIdx.z % S;
    const int q0w = qb * 64 + wid * 16;
    const int cb = s * (T * 64);
    const u16* Qrow = Qb + (long)(b * NQ_ + q0w + h16) * ldq + hh * 64;
    short8 qf0 = *(const short8*)(Qrow + g4 * 8);
    short8 qf1 = *(const short8*)(Qrow + 32 + g4 * 8);
    const u16* Kbase = Kb + (long)b * NCT * ldk + hh * 64;
    const u16* Vtbase = Vtb + (long)(b * H_ + hh) * 64 * ldv;
    const u16* Bbase = Bias + ((long)(b * H_ + hh) * NQ_ + q0w) * NCT;
    u16* mypl = pl[wid];
    const u16* mybl = bl[wid];

    auto stageK = [&](int buf, int c0) {
#pragma unroll
        for (int i = 0; i < 2; ++i) {
            int ch = wid * 128 + i * 64 + lane;
            int row = ch >> 3, col2 = (ch & 7) * 16;
            int scol2 = col2 ^ ((row & 7) << 4);
            gload_lds16(Kbase + (long)(c0 + row) * ldk + (scol2 >> 1), &kl[buf][ch * 8]);
        }
    };
    auto stageV = [&](int c0) {
#pragma unroll
        for (int i = 0; i < 2; ++i) {
            int ch = wid * 128 + i * 64 + lane;
            int row = ch >> 3, col2 = (ch & 7) * 16;
            int scol2 = col2 ^ ((row & 7) << 4);
            gload_lds16(Vtbase + (long)row * ldv + c0 + (scol2 >> 1), &vl[ch * 8]);
        }
    };
    auto stageB = [&](int c0) {
#pragma unroll
        for (int i = 0; i < 2; ++i) {
            int ch = i * 64 + lane;
            int row = ch >> 3, c16 = ch & 7;
            int sc16 = c16 ^ (row & 7);
            gload_lds16(Bbase + (long)row * NCT + c0 + sc16 * 8, &bl[wid][ch * 8]);
        }
    };

    float m0[4] = {-1e30f, -1e30f, -1e30f, -1e30f};
    float l0[4] = {0.f, 0.f, 0.f, 0.f};
    f32x4 oacc[4] = {};
    stageK(0, cb);
    for (int t = 0; t < T; ++t) {
        const int c0 = cb + t * 64, cur = t & 1;
        if (t > 0) {
            asm volatile("s_waitcnt lgkmcnt(0)" ::: "memory");
            __builtin_amdgcn_sched_barrier(0);
            __builtin_amdgcn_s_barrier();
        }
        stageV(c0);
        stageB(c0);
        if (t + 1 < T) stageK(cur ^ 1, c0 + 64);
        if (t + 1 < T) asm volatile("s_waitcnt vmcnt(6)" ::: "memory");
        else           asm volatile("s_waitcnt vmcnt(4)" ::: "memory");
        __builtin_amdgcn_s_barrier();
        f32x4 sacc[4] = {};
        const u16* klc = kl[cur];
        __builtin_amdgcn_s_setprio(1);
#pragma unroll
        for (int n = 0; n < 4; ++n) {
            int row = n * 16 + h16, swz = (row & 7) << 4;
#pragma unroll
            for (int ks = 0; ks < 2; ++ks) {
                short8 kf = *(const short8*)((const char*)klc + row * 128 + ((ks * 64 + g4 * 16) ^ swz));
                sacc[n] = __builtin_amdgcn_mfma_f32_16x16x32_bf16(ks ? qf1 : qf0, kf, sacc[n], 0, 0, 0);
            }
        }
        __builtin_amdgcn_s_setprio(0);
        if (t + 1 < T) asm volatile("s_waitcnt vmcnt(2)" ::: "memory");
        else           asm volatile("s_waitcnt vmcnt(0)" ::: "memory");
        __builtin_amdgcn_s_barrier();
        float cr[4];
#pragma unroll
        for (int r = 0; r < 4; ++r) {
            int q = g4 * 4 + r;
            float mx = -1e30f;
#pragma unroll
            for (int n = 0; n < 4; ++n) {
                float bvv = bf2f(*(const u16*)((const char*)mybl + q * 128 +
                                 (((n * 16 + h16) * 2) ^ ((q & 7) << 4))));
                float sv = sacc[n][r] * SCL2 + bvv;
                sacc[n][r] = sv; mx = fmaxf(mx, sv);
            }
            mx = fmaxf(mx, __shfl_xor(mx, 1)); mx = fmaxf(mx, __shfl_xor(mx, 2));
            mx = fmaxf(mx, __shfl_xor(mx, 4)); mx = fmaxf(mx, __shfl_xor(mx, 8));
            float mn = fmaxf(m0[r], mx);
            cr[r] = __builtin_amdgcn_exp2f(m0[r] - mn); m0[r] = mn;
            float sum = 0.f;
#pragma unroll
            for (int n = 0; n < 4; ++n) {
                float p = __builtin_amdgcn_exp2f(sacc[n][r] - mn); sacc[n][r] = p; sum += p;
            }
            sum += __shfl_xor(sum, 1); sum += __shfl_xor(sum, 2);
            sum += __shfl_xor(sum, 4); sum += __shfl_xor(sum, 8);
            l0[r] = l0[r] * cr[r] + sum;
        }
#pragma unroll
        for (int n = 0; n < 4; ++n)
#pragma unroll
            for (int r = 0; r < 4; ++r) {
                int q = g4 * 4 + r, c = n * 16 + h16;
                *(u16*)((char*)mypl + q * 128 + ((c * 2) ^ ((q & 7) << 4))) =
                    (u16)(__builtin_bit_cast(unsigned int, sacc[n][r]) >> 16);
            }
#pragma unroll
        for (int d = 0; d < 4; ++d) {
            f32x4 o = oacc[d];
            o[0] *= cr[0]; o[1] *= cr[1]; o[2] *= cr[2]; o[3] *= cr[3];
            oacc[d] = o;
        }
        short8 pf[2];
#pragma unroll
        for (int ks = 0; ks < 2; ++ks)
            pf[ks] = *(const short8*)((const char*)mypl + h16 * 128 + ((ks * 64 + g4 * 16) ^ ((h16 & 7) << 4)));
        __builtin_amdgcn_s_setprio(1);
#pragma unroll
        for (int d = 0; d < 4; ++d) {
            int row = d * 16 + h16, swzv = (row & 7) << 4;
#pragma unroll
            for (int ks = 0; ks < 2; ++ks) {
                short8 vf = *(const short8*)((const char*)vl + row * 128 + ((ks * 64 + g4 * 16) ^ swzv));
                oacc[d] = __builtin_amdgcn_mfma_f32_16x16x32_bf16(pf[ks], vf, oacc[d], 0, 0, 0);
            }
        }
        __builtin_amdgcn_s_setprio(0);
    }
    float* P = Part + ((((long)(b * H_ + hh) * 32 + qb * 4 + wid) * S + s) * 1088);
#pragma unroll
    for (int d = 0; d < 4; ++d)
#pragma unroll
        for (int r = 0; r < 4; ++r)
            P[(g4 * 4 + r) * 64 + d * 16 + h16] = oacc[d][r];
    if (h16 == 0) {
#pragma unroll
        for (int r = 0; r < 4; ++r) {
            P[1024 + g4 * 4 + r] = m0[r];
            P[1056 + g4 * 4 + r] = l0[r];
        }
    }
}

// combine S=4 partials -> bf16 output rows (exp2 domain)
__global__ __launch_bounds__(64) void fcomb(const float* __restrict__ Part, u16* __restrict__ Ob) {
    int q16 = blockIdx.x, hh = blockIdx.y, b = blockIdx.z, lane = threadIdx.x;
    const float* base = Part + (((long)(b * H_ + hh) * 32 + q16) * 4) * 1088;
#pragma unroll 4
    for (int q = 0; q < 16; ++q) {
        float m0 = base[1024 + q],        m1 = base[1088 + 1024 + q];
        float m2 = base[2176 + 1024 + q], m3 = base[3264 + 1024 + q];
        float M = fmaxf(fmaxf(m0, m1), fmaxf(m2, m3));
        float w0 = __builtin_amdgcn_exp2f(m0 - M), w1 = __builtin_amdgcn_exp2f(m1 - M);
        float w2 = __builtin_amdgcn_exp2f(m2 - M), w3 = __builtin_amdgcn_exp2f(m3 - M);
        float L = w0 * base[1056 + q] + w1 * base[1088 + 1056 + q] +
                  w2 * base[2176 + 1056 + q] + w3 * base[3264 + 1056 + q];
        float o = w0 * base[q * 64 + lane] + w1 * base[1088 + q * 64 + lane] +
                  w2 * base[2176 + q * 64 + lane] + w3 * base[3264 + q * 64 + lane];
        Ob[(long)(b * NQ_ + q16 * 16 + q) * D_ + hh * 64 + lane] = f2bf(o * (1.f / L));
    }
}

// ---------------- batched bf16 GEMM body, B supplied transposed (N,K) ----------------
enum { EP_BIAS = 0, EP_SCALE = 1, EP_RES = 3, EP_GELU = 4 };

template <int BM, int BN, int EPI>
__device__ __forceinline__ void gemm_body(
    u16* lA, u16* lB,
    const u16* __restrict__ A, const u16* __restrict__ B, void* __restrict__ Cv,
    const float* __restrict__ bias, const float* __restrict__ res,
    int M, int N, int K, int lda, int ldb, int ldc,
    int bdiv, long sAb, long sAh, long sBb, long sBh, long sCb, long sCh,
    float scale, int biasz, int bx, int by, int z, int tid) {
    constexpr int BK = 64;
    const int zb = z / bdiv, zh = z % bdiv;
    const u16* Ab = A + zb * sAb + zh * sAh;
    const u16* Bb = B + zb * sBb + zh * sBh;
    const int bm = by * BM;
    const int bn = bx * BN;
    const int lane = tid & 63, wid = tid >> 6;
    const int wm = (wid >> 1) * (BM / 2);
    const int wn = (wid & 1) * (BN / 2);
    constexpr int FM = BM / 32, FN = BN / 32;
    f32x4 acc[FM][FN] = {};
    const int lrow = lane & 15, lk = (lane >> 4) * 8;

    for (int kb = 0; kb < K; kb += BK) {
#pragma unroll
        for (int i = 0; i < (BM * 8) / 256; ++i) {
            int ch = tid + i * 256;
            int r = ch >> 3, c = ch & 7;
            gload_lds16(Ab + (long)(bm + r) * lda + kb + c * 8, lA + ch * 8);
        }
#pragma unroll
        for (int i = 0; i < (BN * 8) / 256; ++i) {
            int ch = tid + i * 256;
            int r = ch >> 3, c = ch & 7;
            gload_lds16(Bb + (long)(bn + r) * ldb + kb + c * 8, lB + ch * 8);
        }
        __syncthreads();
#pragma unroll
        for (int ks = 0; ks < 2; ++ks) {
            short8 af[FM], bfr[FN];
#pragma unroll
            for (int i = 0; i < FM; ++i)
                af[i] = *(const short8*)(lA + (wm + i * 16 + lrow) * BK + ks * 32 + lk);
#pragma unroll
            for (int j = 0; j < FN; ++j)
                bfr[j] = *(const short8*)(lB + (wn + j * 16 + lrow) * BK + ks * 32 + lk);
#pragma unroll
            for (int i = 0; i < FM; ++i)
#pragma unroll
                for (int j = 0; j < FN; ++j)
                    acc[i][j] = __builtin_amdgcn_mfma_f32_16x16x32_bf16(af[i], bfr[j], acc[i][j], 0, 0, 0);
        }
        __syncthreads();
    }

    long coff = zb * sCb + zh * sCh;
#pragma unroll
    for (int i = 0; i < FM; ++i) {
#pragma unroll
        for (int j = 0; j < FN; ++j) {
#pragma unroll
            for (int r = 0; r < 4; ++r) {
                int row = bm + wm + i * 16 + (lane >> 4) * 4 + r;
                int col = bn + wn + j * 16 + (lane & 15);
                long idx = coff + (long)row * ldc + col;
                float v = acc[i][j][r];
                if (EPI == EP_SCALE) {
                    ((u16*)Cv)[idx] = f2bf(v * scale);
                } else if (EPI == EP_RES) {
                    float tt = v + (bias ? bias[col] : 0.f);
                    ((float*)Cv)[idx] = res[idx] + tt;
                } else if (EPI == EP_GELU) {
                    float tt = v + (bias ? bias[col] : 0.f);
                    ((u16*)Cv)[idx] = f2bf(gelu_f(tt));
                } else {
                    float tt = v + (bias ? bias[biasz * zb + col] : 0.f);
                    ((u16*)Cv)[idx] = f2bf(tt);
                }
            }
        }
    }
}

template <int BM, int BN, int EPI>
__global__ __launch_bounds__(256) void gemm_bt(
    const u16* __restrict__ A, const u16* __restrict__ B, void* __restrict__ Cv,
    const float* __restrict__ bias, const float* __restrict__ res,
    int M, int N, int K, int lda, int ldb, int ldc,
    int bdiv, long sAb, long sAh, long sBb, long sBh, long sCb, long sCh,
    float scale, int biasz) {
    __shared__ u16 lA[BM * 64];
    __shared__ u16 lB[BN * 64];
    gemm_body<BM, BN, EPI>(lA, lB, A, B, Cv, bias, res, M, N, K, lda, ldb, ldc,
                           bdiv, sAb, sAh, sBb, sBh, sCb, sCh, scale, biasz,
                           blockIdx.x, blockIdx.y, blockIdx.z, threadIdx.x);
}

// ---------------- fused: merged KV projection (blocks 0..767) + bias MLP (768..2815) ----------------
__global__ __launch_bounds__(256) void kvproj_bias(
    const u16* __restrict__ ckb, const u16* __restrict__ wT_k, u16* __restrict__ kc,
    const float* __restrict__ bkv,
    const float* __restrict__ qcoord, const float* __restrict__ ccoord,
    const float* __restrict__ rb_w1, const float* __restrict__ rb_b1,
    const float* __restrict__ rb_w2, const float* __restrict__ rb_b2,
    u16* __restrict__ clog) {
    __shared__ __attribute__((aligned(16))) char smem[(64 + 128) * 64 * 2];
    int idx = blockIdx.x, tid = threadIdx.x;
    if (idx < 768) {
        int z = idx / 384, rem = idx % 384;
        int bx = rem % 6, by = rem / 6;
        gemm_body<64, 128, EP_BIAS>((u16*)smem, (u16*)(smem + 64 * 64 * 2),
            ckb, wT_k, kc, bkv, nullptr, 4096, 768, 768, 768, 768, 768,
            1, (long)B_ * NC_ * D_, 0, (long)768 * 768, 0, (long)4096 * 768, 0,
            1.f, 768, bx, by, z, tid);
    } else {
        int bidx = idx - 768;
        int cx = bidx & 7, q4 = (bidx >> 3) & 127, b = bidx >> 10;
        bias_body(smem, qcoord, ccoord, rb_w1, rb_b1, rb_w2, rb_b2, clog, cx, q4, b, tid);
    }
}

extern "C" void kernel_launch(void* const* d_in, const int* in_sizes, int n_in,
                              void* d_out, int out_size, void* d_ws, size_t ws_size,
                              hipStream_t stream) {
    const float* x_in   = (const float*)d_in[0];
    const float* ctx_k  = (const float*)d_in[1];
    const float* ctx_v  = (const float*)d_in[2];
    const float* qcoord = (const float*)d_in[3];
    const float* ccoord = (const float*)d_in[4];
    const float* sn_g   = (const float*)d_in[5];
    const float* sn_b   = (const float*)d_in[6];
    const float* wqkv   = (const float*)d_in[7];
    const float* bqkv   = (const float*)d_in[8];
    const float* wo_s   = (const float*)d_in[9];
    const float* bo_s   = (const float*)d_in[10];
    const float* cn_g   = (const float*)d_in[11];
    const float* cn_b   = (const float*)d_in[12];
    const float* wq     = (const float*)d_in[13];
    const float* bq     = (const float*)d_in[14];
    const float* wk     = (const float*)d_in[15];
    const float* bk     = (const float*)d_in[16];
    const float* wv     = (const float*)d_in[17];
    const float* bv     = (const float*)d_in[18];
    const float* wo_c   = (const float*)d_in[19];
    const float* bo_c   = (const float*)d_in[20];
    const float* rb_w1  = (const float*)d_in[21];
    const float* rb_b1  = (const float*)d_in[22];
    const float* rb_w2  = (const float*)d_in[23];
    const float* rb_b2  = (const float*)d_in[24];
    const float* fn_g   = (const float*)d_in[25];
    const float* fn_b   = (const float*)d_in[26];
    const float* fw1    = (const float*)d_in[27];
    const float* fb1    = (const float*)d_in[28];
    const float* fw2    = (const float*)d_in[29];
    const float* fb2    = (const float*)d_in[30];

    char* ws = (char*)d_ws;
    size_t off = 0;
    auto alloc = [&](size_t bytes) -> void* {
        void* p = ws + off; off += (bytes + 255) & ~(size_t)255; return p;
    };
    u16* wT_qkv = (u16*)alloc((size_t)2304 * 768 * 2);
    u16* wT_os  = (u16*)alloc((size_t)768 * 768 * 2);
    u16* wT_q   = (u16*)alloc((size_t)768 * 768 * 2);
    u16* wT_k   = (u16*)alloc((size_t)768 * 768 * 2);   // adjacent to wT_v (sBb)
    u16* wT_v   = (u16*)alloc((size_t)768 * 768 * 2);
    u16* wT_oc  = (u16*)alloc((size_t)768 * 768 * 2);
    u16* wT_f1  = (u16*)alloc((size_t)3072 * 768 * 2);
    u16* wT_f2  = (u16*)alloc((size_t)768 * 3072 * 2);
    u16* ckb    = (u16*)alloc((size_t)B_ * NC_ * D_ * 2);  // adjacent to cvb (sAb)
    u16* cvb    = (u16*)alloc((size_t)B_ * NC_ * D_ * 2);
    u16* xln    = (u16*)alloc((size_t)1024 * 768 * 2);
    u16* qkv    = (u16*)alloc((size_t)1024 * 2304 * 2);
    u16* vts    = (u16*)alloc((size_t)24 * 64 * 512 * 2);
    u16* oatt   = (u16*)alloc((size_t)1024 * 768 * 2);
    float* x1   = (float*)alloc((size_t)1024 * 768 * 4);
    u16* xln2   = (u16*)alloc((size_t)1024 * 768 * 2);
    u16* qc     = (u16*)alloc((size_t)1024 * 768 * 2);
    u16* kc     = (u16*)alloc((size_t)4096 * 768 * 2);  // adjacent to vc (sCb)
    u16* vc     = (u16*)alloc((size_t)4096 * 768 * 2);
    u16* clog   = (u16*)alloc((size_t)24 * 512 * 2048 * 2);
    u16* vtc    = (u16*)alloc((size_t)24 * 64 * 2048 * 2);
    u16* oc2    = (u16*)alloc((size_t)1024 * 768 * 2);
    float* x2   = (float*)alloc((size_t)1024 * 768 * 4);
    u16* xln3   = (u16*)alloc((size_t)1024 * 768 * 2);
    u16* ffh    = (u16*)alloc((size_t)1024 * 3072 * 2);
    float* part = (float*)alloc((size_t)2 * H_ * 32 * 4 * 1088 * 4);
    float* bkv  = (float*)alloc((size_t)1536 * 4);
    (void)ws_size; (void)in_sizes; (void)n_in; (void)out_size;

    // merged prep: all transposes + context bf16 convert + bias concat
    prep<<<15366, 256, 0, stream>>>(wqkv, wT_qkv, wo_s, wq, wk, wv, wo_c,
                                    wT_os, wT_q, wT_k, wT_v, wT_oc,
                                    fw1, wT_f1, fw2, wT_f2,
                                    ctx_k, ckb, ctx_v, cvb, bk, bv, bkv);

    // ---- self attention ----
    ln_k<<<1024, 256, 0, stream>>>(x_in, sn_g, sn_b, xln);
    gemm_bt<64, 128, EP_BIAS><<<dim3(2304 / 128, 1024 / 64, 1), 256, 0, stream>>>(
        xln, wT_qkv, qkv, bqkv, nullptr, 1024, 2304, 768, 768, 768, 2304,
        1, 0, 0, 0, 0, 0, 0, 1.f, 0);
    vtrans<<<dim3(512 / 32, 2, 24), 256, 0, stream>>>(qkv + 1536, vts, 512, 2304, 12, (long)512 * 2304, 64);
    fattn<512, false><<<dim3(NQ_ / 16, H_, B_), 64, 0, stream>>>(
        qkv, qkv + 768, vts, nullptr, oatt, 2304, 2304);
    gemm_bt<32, 64, EP_RES><<<dim3(768 / 64, 1024 / 32, 1), 256, 0, stream>>>(
        oatt, wT_os, x1, bo_s, x_in, 1024, 768, 768, 768, 768, 768,
        1, 0, 0, 0, 0, 0, 0, 1.f, 0);

    // ---- cross attention ----
    ln_k<<<1024, 256, 0, stream>>>(x1, cn_g, cn_b, xln2);
    gemm_bt<32, 64, EP_BIAS><<<dim3(768 / 64, 1024 / 32, 1), 256, 0, stream>>>(
        xln2, wT_q, qc, bq, nullptr, 1024, 768, 768, 768, 768, 768,
        1, 0, 0, 0, 0, 0, 0, 1.f, 0);
    // fused: merged K/V projection + relative-bias MLP (independent work, VALU/MFMA overlap)
    kvproj_bias<<<2816, 256, 0, stream>>>(ckb, wT_k, kc, bkv,
                                          qcoord, ccoord, rb_w1, rb_b1, rb_w2, rb_b2, clog);
    vtrans<<<dim3(2048 / 32, 2, 24), 256, 0, stream>>>(vc, vtc, 2048, 768, 12, (long)2048 * 768, 64);
    fattn4<8, 4><<<dim3(8, H_, B_ * 4), 256, 0, stream>>>(
        qc, kc, vtc, clog, part, 768, 768, 2048, 2048);
    fcomb<<<dim3(32, H_, B_), 64, 0, stream>>>(part, oc2);
    gemm_bt<32, 64, EP_RES><<<dim3(768 / 64, 1024 / 32, 1), 256, 0, stream>>>(
        oc2, wT_oc, x2, bo_c, x1, 1024, 768, 768, 768, 768, 768,
        1, 0, 0, 0, 0, 0, 0, 1.f, 0);

    // ---- FFN ----
    ln_k<<<1024, 256, 0, stream>>>(x2, fn_g, fn_b, xln3);
    gemm_bt<64, 128, EP_GELU><<<dim3(3072 / 128, 1024 / 64, 1), 256, 0, stream>>>(
        xln3, wT_f1, ffh, fb1, nullptr, 1024, 3072, 768, 768, 768, 3072,
        1, 0, 0, 0, 0, 0, 0, 1.f, 0);
    gemm_bt<32, 64, EP_RES><<<dim3(768 / 64, 1024 / 32, 1), 256, 0, stream>>>(
        ffh, wT_f2, (float*)d_out, fb2, x2, 1024, 768, 3072, 3072, 3072, 768,
        1, 0, 0, 0, 0, 0, 0, 1.f, 0);
}

// Round 13
// 239.053 us; speedup vs baseline: 1.1356x; 1.0123x over previous
//
#include <hip/hip_runtime.h>

#define B_ 2
#define NQ_ 512
#define NC_ 2048
#define D_ 768
#define H_ 12
#define HD_ 64
#define FF_ 3072
#define RB_ 64

typedef unsigned short u16;
typedef __attribute__((ext_vector_type(4))) unsigned short u16x4;
typedef __attribute__((ext_vector_type(8))) short short8;
typedef __attribute__((ext_vector_type(4))) float f32x4;
typedef __attribute__((ext_vector_type(2))) float f32x2;

#define SCL2 0.18033688f   /* 0.125 * log2(e) */

__device__ __forceinline__ float bf2f(u16 u) {
    unsigned int i = ((unsigned int)u) << 16;
    float f; __builtin_memcpy(&f, &i, 4); return f;
}
__device__ __forceinline__ u16 f2bf(float f) {
    unsigned int i; __builtin_memcpy(&i, &f, 4);
    unsigned int r = i + 0x7FFFu + ((i >> 16) & 1u);
    return (u16)(r >> 16);
}
__device__ __forceinline__ float gelu_f(float x) {
    return 0.5f * x * (1.f + erff(x * 0.70710678118654752f));
}
__device__ __forceinline__ float wsum(float v) {
    v += __shfl_xor(v, 32); v += __shfl_xor(v, 16); v += __shfl_xor(v, 8);
    v += __shfl_xor(v, 4);  v += __shfl_xor(v, 2);  v += __shfl_xor(v, 1);
    return v;
}
__device__ __forceinline__ void gload_lds16(const void* g, void* l) {
    __builtin_amdgcn_global_load_lds((const __attribute__((address_space(1))) void*)g,
                                     (__attribute__((address_space(3))) void*)l, 16, 0, 0);
}

// ---------------- weight transpose body: (K,N) f32 -> (N,K) bf16 ----------------
__device__ __forceinline__ void wtrans_body(const float* __restrict__ in, u16* __restrict__ out,
                                            int K, int N, int bx, int by, int tid) {
    __shared__ float t[32][33];
    int n0 = bx * 32, k0 = by * 32;
    int tx = tid & 31, ty = tid >> 5;
#pragma unroll
    for (int r = 0; r < 4; ++r)
        t[ty + r * 8][tx] = in[(long)(k0 + ty + r * 8) * N + n0 + tx];
    __syncthreads();
#pragma unroll
    for (int r = 0; r < 4; ++r)
        out[(long)(n0 + ty + r * 8) * K + k0 + tx] = f2bf(t[tx][ty + r * 8]);
}

// ---------------- merged prep: all weight transposes + ctx converts + bias concat ----------------
__global__ __launch_bounds__(256) void prep(
    const float* wqkv, u16* wT_qkv,
    const float* wo_s, const float* wq, const float* wk, const float* wv, const float* wo_c,
    u16* wT_os, u16* wT_q, u16* wT_k, u16* wT_v, u16* wT_oc,
    const float* fw1, u16* wT_f1, const float* fw2, u16* wT_f2,
    const float* ctx_k, u16* ckb, const float* ctx_v, u16* cvb,
    const float* bk, const float* bv, float* bkv) {
    int i = blockIdx.x, tid = threadIdx.x;
    if (i < 1728) { wtrans_body(wqkv, wT_qkv, 768, 2304, i % 72, i / 72, tid); return; }
    i -= 1728;
    if (i < 2880) {
        int z = i / 576, rem = i % 576;
        const float* in; u16* out;
        switch (z) {
            case 0: in = wo_s; out = wT_os; break;
            case 1: in = wq;   out = wT_q;  break;
            case 2: in = wk;   out = wT_k;  break;
            case 3: in = wv;   out = wT_v;  break;
            default: in = wo_c; out = wT_oc; break;
        }
        wtrans_body(in, out, 768, 768, rem % 24, rem / 24, tid);
        return;
    }
    i -= 2880;
    if (i < 2304) { wtrans_body(fw1, wT_f1, 768, 3072, i % 96, i / 96, tid); return; }
    i -= 2304;
    if (i < 2304) { wtrans_body(fw2, wT_f2, 3072, 768, i % 24, i / 24, tid); return; }
    i -= 2304;
    if (i < 6144) {
        int y = i / 3072;
        int ii = (i % 3072) * 256 + tid;
        const float* in = y ? ctx_v : ctx_k;
        u16* out = y ? cvb : ckb;
        float4 v = ((const float4*)in)[ii];
        u16x4 o; o.x = f2bf(v.x); o.y = f2bf(v.y); o.z = f2bf(v.z); o.w = f2bf(v.w);
        ((u16x4*)out)[ii] = o;
        return;
    }
    i -= 6144;
    {
        int j = i * 256 + tid;
        if (j < 768) bkv[j] = bk[j];
        else if (j < 1536) bkv[j] = bv[j - 768];
    }
}

// ---------------- LayerNorm: f32 in -> bf16 out, rows of D_=768 ----------------
__global__ __launch_bounds__(256) void ln_k(const float* __restrict__ x, const float* __restrict__ g,
                                            const float* __restrict__ bta, u16* __restrict__ out) {
    int row = blockIdx.x, t = threadIdx.x;
    const float* xr = x + (long)row * D_;
    float a0 = xr[t], a1 = xr[t + 256], a2 = xr[t + 512];
    float s = a0 + a1 + a2, s2 = a0 * a0 + a1 * a1 + a2 * a2;
    s = wsum(s); s2 = wsum(s2);
    __shared__ float rb[8];
    int lane = t & 63, wid = t >> 6;
    if (!lane) { rb[wid] = s; rb[wid + 4] = s2; }
    __syncthreads();
    float S = rb[0] + rb[1] + rb[2] + rb[3];
    float S2 = rb[4] + rb[5] + rb[6] + rb[7];
    float mean = S * (1.f / D_);
    float var = S2 * (1.f / D_) - mean * mean;
    float rstd = rsqrtf(var + 1e-5f);
    u16* orow = out + (long)row * D_;
    orow[t]       = f2bf((a0 - mean) * rstd * g[t]       + bta[t]);
    orow[t + 256] = f2bf((a1 - mean) * rstd * g[t + 256] + bta[t + 256]);
    orow[t + 512] = f2bf((a2 - mean) * rstd * g[t + 512] + bta[t + 512]);
}

// ---------------- relative-bias MLP v7 (standalone, small LDS, high occupancy) ----------------
__global__ __launch_bounds__(256) void bias_mlp7(
    const float* __restrict__ qcoord, const float* __restrict__ ccoord,
    const float* __restrict__ w1, const float* __restrict__ b1,
    const float* __restrict__ w2, const float* __restrict__ b2,
    u16* __restrict__ out) {
    __shared__ float s1[192];
    __shared__ float sw2[RB_ * H_];
    __shared__ float2 sc[256];
    __shared__ u16 sb[12 * 264];
    int tid = threadIdx.x;
    int b = blockIdx.z, q0 = blockIdx.y * 4, c0 = blockIdx.x * 256;
    if (tid < 64) { s1[tid] = w1[tid]; s1[64 + tid] = w1[64 + tid]; s1[128 + tid] = b1[tid]; }
    for (int i = tid; i < RB_ * H_; i += 256) sw2[i] = w2[i];
    sc[tid] = ((const float2*)ccoord)[b * NC_ + c0 + tid];
    __syncthreads();
    int lane = tid & 63, wid = tid >> 6;
    int h = lane & 15, g4 = lane >> 4;
    int j0 = g4 * 8;
    f32x2 wx[8], wy[8], bb[8];
#pragma unroll
    for (int p = 0; p < 4; ++p) {
        wx[p]     = (f32x2){s1[j0 + 2 * p],       s1[j0 + 2 * p + 1]};
        wy[p]     = (f32x2){s1[64 + j0 + 2 * p],  s1[64 + j0 + 2 * p + 1]};
        bb[p]     = (f32x2){s1[128 + j0 + 2 * p], s1[128 + j0 + 2 * p + 1]};
        wx[4 + p] = (f32x2){s1[32 + j0 + 2 * p],  s1[32 + j0 + 2 * p + 1]};
        wy[4 + p] = (f32x2){s1[96 + j0 + 2 * p],  s1[96 + j0 + 2 * p + 1]};
        bb[4 + p] = (f32x2){s1[160 + j0 + 2 * p], s1[160 + j0 + 2 * p + 1]};
    }
    short8 vb0, vb1;
#pragma unroll
    for (int u = 0; u < 8; ++u) {
        vb0[u] = (h < 12) ? (short)f2bf(sw2[(j0 + u) * H_ + h]) : (short)0;
        vb1[u] = (h < 12) ? (short)f2bf(sw2[(32 + j0 + u) * H_ + h]) : (short)0;
    }
    float qx[4], qy[4];
#pragma unroll
    for (int qq = 0; qq < 4; ++qq) {
        qx[qq] = qcoord[(b * NQ_ + q0 + qq) * 2];
        qy[qq] = qcoord[(b * NQ_ + q0 + qq) * 2 + 1];
    }
    float b2v = (h < 12) ? b2[h] : 0.f;
#pragma unroll 1
    for (int qq = 0; qq < 4; ++qq) {
        if (qq) __syncthreads();
#pragma unroll
        for (int it = 0; it < 4; ++it) {
            int ci = wid * 64 + it * 16 + h;
            float2 cc = sc[ci];
            float dx = qx[qq] - cc.x, dy = qy[qq] - cc.y;
            unsigned int pk[8];
#pragma unroll
            for (int p = 0; p < 8; ++p) {
                f32x2 pre = dx * wx[p] + bb[p];
                pre = dy * wy[p] + pre;
                f32x2 xc = __builtin_elementwise_min(
                               __builtin_elementwise_max(pre, (f32x2)(-3.0f)), (f32x2)(3.0f));
                f32x2 u = xc * xc;
                f32x2 v = u * 2.3813e-5f + (-6.8939e-4f);
                v = v * u + 0.0086261f;
                v = v * u + (-0.064949f);
                v = v * u + 0.39837f;
                f32x2 phi = xc * v + 0.5f;
                f32x2 g = pre * phi;
                pk[p] = __builtin_amdgcn_perm(__builtin_bit_cast(unsigned int, g.y),
                                              __builtin_bit_cast(unsigned int, g.x), 0x07060302u);
            }
            uint4 d0 = {pk[0], pk[1], pk[2], pk[3]};
            uint4 d1 = {pk[4], pk[5], pk[6], pk[7]};
            short8 a0 = __builtin_bit_cast(short8, d0);
            short8 a1 = __builtin_bit_cast(short8, d1);
            f32x4 acc = {};
            acc = __builtin_amdgcn_mfma_f32_16x16x32_bf16(a0, vb0, acc, 0, 0, 0);
            acc = __builtin_amdgcn_mfma_f32_16x16x32_bf16(a1, vb1, acc, 0, 0, 0);
            if (h < 12) {
#pragma unroll
                for (int r = 0; r < 4; ++r) {
                    int loc = wid * 64 + it * 16 + g4 * 4 + r;
                    sb[h * 264 + loc] = f2bf((acc[r] + b2v) * 1.4426950f);
                }
            }
        }
        __syncthreads();
        for (int i = tid; i < 12 * 128; i += 256) {
            int row = i >> 7, cp = (i & 127) * 2;
            unsigned int pv = *(const unsigned int*)(sb + row * 264 + cp);
            *(unsigned int*)(out + (((long)(b * H_ + row) * NQ_ + q0 + qq) * NC_ + c0 + cp)) = pv;
        }
    }
}

// ---------------- bf16 strided transpose for V-slices ----------------
__global__ __launch_bounds__(256) void vtrans(const u16* __restrict__ in, u16* __restrict__ out,
                                              int NCt, int ldin, int bdiv, long sIb, long sIh) {
    __shared__ u16 t[32][33];
    int z = blockIdx.z, zb = z / bdiv, zh = z % bdiv;
    const u16* ib = in + zb * sIb + zh * sIh;
    int c0 = blockIdx.x * 32, d0 = blockIdx.y * 32;
    int tx = threadIdx.x & 31, ty = threadIdx.x >> 5;
#pragma unroll
    for (int r = 0; r < 4; ++r)
        t[ty + r * 8][tx] = ib[(long)(c0 + ty + r * 8) * ldin + d0 + tx];
    __syncthreads();
#pragma unroll
    for (int r = 0; r < 4; ++r)
        out[(long)z * 64 * NCt + (long)(d0 + ty + r * 8) * NCt + c0 + tx] = t[tx][ty + r * 8];
}

// ---------------- 1-wave flash attention (self-attn, no bias) ----------------
template <int NCT, bool HASBIAS>
__global__ __launch_bounds__(64) void fattn(
    const u16* __restrict__ Qb, const u16* __restrict__ Kb, const u16* __restrict__ Vtb,
    const u16* __restrict__ Bias, u16* __restrict__ Ob, int ldq, int ldk) {
    __shared__ u16 kl[2][128 * 64];
    __shared__ u16 vl[64 * 128];
    __shared__ u16 pl[16 * 128];
    const int lane = threadIdx.x;
    const int h16 = lane & 15, g4 = lane >> 4;
    const int hh = blockIdx.y, b = blockIdx.z, q0 = blockIdx.x * 16;
    const u16* Qrow = Qb + (long)(b * NQ_ + q0 + h16) * ldq + hh * 64;
    short8 qf0 = *(const short8*)(Qrow + g4 * 8);
    short8 qf1 = *(const short8*)(Qrow + 32 + g4 * 8);
    const u16* Kbase = Kb + (long)b * NCT * ldk + hh * 64;
    const u16* Vtbase = Vtb + (long)(b * H_ + hh) * 64 * NCT;

    auto stageK = [&](int buf, int c0) {
#pragma unroll
        for (int i = 0; i < 16; ++i) {
            int ch = i * 64 + lane;
            int row = ch >> 3, col2 = (ch & 7) * 16;
            int scol2 = col2 ^ ((row & 7) << 4);
            gload_lds16(Kbase + (long)(c0 + row) * ldk + (scol2 >> 1), &kl[buf][ch * 8]);
        }
    };
    auto stageV = [&](int c0) {
#pragma unroll
        for (int i = 0; i < 16; ++i) {
            int ch = i * 64 + lane;
            int row = ch >> 4, col2 = (ch & 15) * 16;
            int scol2 = col2 ^ ((row & 15) << 4);
            gload_lds16(Vtbase + (long)row * NCT + c0 + (scol2 >> 1), &vl[ch * 8]);
        }
    };

    float m0[4] = {-1e30f, -1e30f, -1e30f, -1e30f};
    float l0[4] = {0.f, 0.f, 0.f, 0.f};
    f32x4 oacc[4] = {};
    constexpr int T = NCT / 128;
    stageK(0, 0);
    for (int t = 0; t < T; ++t) {
        const int c0 = t * 128, cur = t & 1;
        asm volatile("s_waitcnt lgkmcnt(0)" ::: "memory");
        stageV(c0);
        if (t + 1 < T) stageK(cur ^ 1, c0 + 128);
        if (t + 1 < T) asm volatile("s_waitcnt vmcnt(32)" ::: "memory");
        else           asm volatile("s_waitcnt vmcnt(16)" ::: "memory");
        f32x4 sacc[8] = {};
        const u16* klc = kl[cur];
        __builtin_amdgcn_s_setprio(1);
#pragma unroll
        for (int n = 0; n < 8; ++n) {
            int row = n * 16 + h16, swz = (row & 7) << 4;
#pragma unroll
            for (int ks = 0; ks < 2; ++ks) {
                short8 kf = *(const short8*)((const char*)klc + row * 128 + ((ks * 64 + g4 * 16) ^ swz));
                sacc[n] = __builtin_amdgcn_mfma_f32_16x16x32_bf16(ks ? qf1 : qf0, kf, sacc[n], 0, 0, 0);
            }
        }
        __builtin_amdgcn_s_setprio(0);
        if (t + 1 < T) asm volatile("s_waitcnt vmcnt(16)" ::: "memory");
        else           asm volatile("s_waitcnt vmcnt(0)" ::: "memory");
        float cr[4];
#pragma unroll
        for (int r = 0; r < 4; ++r) {
            float mx = -1e30f;
#pragma unroll
            for (int n = 0; n < 8; ++n) {
                float s = sacc[n][r] * SCL2;
                sacc[n][r] = s; mx = fmaxf(mx, s);
            }
            mx = fmaxf(mx, __shfl_xor(mx, 1)); mx = fmaxf(mx, __shfl_xor(mx, 2));
            mx = fmaxf(mx, __shfl_xor(mx, 4)); mx = fmaxf(mx, __shfl_xor(mx, 8));
            float mn = fmaxf(m0[r], mx);
            cr[r] = __builtin_amdgcn_exp2f(m0[r] - mn); m0[r] = mn;
            float sum = 0.f;
#pragma unroll
            for (int n = 0; n < 8; ++n) {
                float p = __builtin_amdgcn_exp2f(sacc[n][r] - mn); sacc[n][r] = p; sum += p;
            }
            sum += __shfl_xor(sum, 1); sum += __shfl_xor(sum, 2);
            sum += __shfl_xor(sum, 4); sum += __shfl_xor(sum, 8);
            l0[r] = l0[r] * cr[r] + sum;
        }
#pragma unroll
        for (int n = 0; n < 8; ++n)
#pragma unroll
            for (int r = 0; r < 4; ++r) {
                int q = g4 * 4 + r, c = n * 16 + h16;
                *(u16*)((char*)pl + q * 256 + ((c * 2) ^ (q << 4))) =
                    (u16)(__builtin_bit_cast(unsigned int, sacc[n][r]) >> 16);
            }
#pragma unroll
        for (int d = 0; d < 4; ++d) {
            f32x4 o = oacc[d];
            o[0] *= cr[0]; o[1] *= cr[1]; o[2] *= cr[2]; o[3] *= cr[3];
            oacc[d] = o;
        }
        short8 pf[4];
#pragma unroll
        for (int ks = 0; ks < 4; ++ks)
            pf[ks] = *(const short8*)((const char*)pl + h16 * 256 + ((ks * 64 + g4 * 16) ^ (h16 << 4)));
        __builtin_amdgcn_s_setprio(1);
#pragma unroll
        for (int d = 0; d < 4; ++d) {
            int row = d * 16 + h16, swzv = (row & 15) << 4;
#pragma unroll
            for (int ks = 0; ks < 4; ++ks) {
                short8 vf = *(const short8*)((const char*)vl + row * 256 + ((ks * 64 + g4 * 16) ^ swzv));
                oacc[d] = __builtin_amdgcn_mfma_f32_16x16x32_bf16(pf[ks], vf, oacc[d], 0, 0, 0);
            }
        }
        __builtin_amdgcn_s_setprio(0);
    }
    float inv[4];
#pragma unroll
    for (int r = 0; r < 4; ++r) inv[r] = 1.f / l0[r];
    u16* Orow = Ob + (long)(b * NQ_ + q0) * D_ + hh * 64;
#pragma unroll
    for (int d = 0; d < 4; ++d)
#pragma unroll
        for (int r = 0; r < 4; ++r)
            Orow[(long)(g4 * 4 + r) * D_ + d * 16 + h16] = f2bf(oacc[d][r] * inv[r]);
}

// ---------------- 4-wave split-context flash attention with bias (KVBLK=64) ----------------
template <int T, int S>
__global__ __launch_bounds__(256) void fattn4(
    const u16* __restrict__ Qb, const u16* __restrict__ Kb, const u16* __restrict__ Vtb,
    const u16* __restrict__ Bias, float* __restrict__ Part,
    int ldq, int ldk, int ldv, int NCT) {
    __shared__ u16 kl[2][64 * 64];
    __shared__ u16 vl[64 * 64];
    __shared__ u16 bl[4][16 * 64];
    __shared__ u16 pl[4][16 * 64];
    const int tid = threadIdx.x, lane = tid & 63, wid = tid >> 6;
    const int h16 = lane & 15, g4 = lane >> 4;
    const int qb = blockIdx.x, hh = blockIdx.y;
    const int b = blockIdx.z / S, s = blockIdx.z % S;
    const int q0w = qb * 64 + wid * 16;
    const int cb = s * (T * 64);
    const u16* Qrow = Qb + (long)(b * NQ_ + q0w + h16) * ldq + hh * 64;
    short8 qf0 = *(const short8*)(Qrow + g4 * 8);
    short8 qf1 = *(const short8*)(Qrow + 32 + g4 * 8);
    const u16* Kbase = Kb + (long)b * NCT * ldk + hh * 64;
    const u16* Vtbase = Vtb + (long)(b * H_ + hh) * 64 * ldv;
    const u16* Bbase = Bias + ((long)(b * H_ + hh) * NQ_ + q0w) * NCT;
    u16* mypl = pl[wid];
    const u16* mybl = bl[wid];

    auto stageK = [&](int buf, int c0) {
#pragma unroll
        for (int i = 0; i < 2; ++i) {
            int ch = wid * 128 + i * 64 + lane;
            int row = ch >> 3, col2 = (ch & 7) * 16;
            int scol2 = col2 ^ ((row & 7) << 4);
            gload_lds16(Kbase + (long)(c0 + row) * ldk + (scol2 >> 1), &kl[buf][ch * 8]);
        }
    };
    auto stageV = [&](int c0) {
#pragma unroll
        for (int i = 0; i < 2; ++i) {
            int ch = wid * 128 + i * 64 + lane;
            int row = ch >> 3, col2 = (ch & 7) * 16;
            int scol2 = col2 ^ ((row & 7) << 4);
            gload_lds16(Vtbase + (long)row * ldv + c0 + (scol2 >> 1), &vl[ch * 8]);
        }
    };
    auto stageB = [&](int c0) {
#pragma unroll
        for (int i = 0; i < 2; ++i) {
            int ch = i * 64 + lane;
            int row = ch >> 3, c16 = ch & 7;
            int sc16 = c16 ^ (row & 7);
            gload_lds16(Bbase + (long)row * NCT + c0 + sc16 * 8, &bl[wid][ch * 8]);
        }
    };

    float m0[4] = {-1e30f, -1e30f, -1e30f, -1e30f};
    float l0[4] = {0.f, 0.f, 0.f, 0.f};
    f32x4 oacc[4] = {};
    stageK(0, cb);
    for (int t = 0; t < T; ++t) {
        const int c0 = cb + t * 64, cur = t & 1;
        if (t > 0) {
            asm volatile("s_waitcnt lgkmcnt(0)" ::: "memory");
            __builtin_amdgcn_sched_barrier(0);
            __builtin_amdgcn_s_barrier();
        }
        stageV(c0);
        stageB(c0);
        if (t + 1 < T) stageK(cur ^ 1, c0 + 64);
        if (t + 1 < T) asm volatile("s_waitcnt vmcnt(6)" ::: "memory");
        else           asm volatile("s_waitcnt vmcnt(4)" ::: "memory");
        __builtin_amdgcn_s_barrier();
        f32x4 sacc[4] = {};
        const u16* klc = kl[cur];
        __builtin_amdgcn_s_setprio(1);
#pragma unroll
        for (int n = 0; n < 4; ++n) {
            int row = n * 16 + h16, swz = (row & 7) << 4;
#pragma unroll
            for (int ks = 0; ks < 2; ++ks) {
                short8 kf = *(const short8*)((const char*)klc + row * 128 + ((ks * 64 + g4 * 16) ^ swz));
                sacc[n] = __builtin_amdgcn_mfma_f32_16x16x32_bf16(ks ? qf1 : qf0, kf, sacc[n], 0, 0, 0);
            }
        }
        __builtin_amdgcn_s_setprio(0);
        if (t + 1 < T) asm volatile("s_waitcnt vmcnt(2)" ::: "memory");
        else           asm volatile("s_waitcnt vmcnt(0)" ::: "memory");
        __builtin_amdgcn_s_barrier();
        float cr[4];
#pragma unroll
        for (int r = 0; r < 4; ++r) {
            int q = g4 * 4 + r;
            float mx = -1e30f;
#pragma unroll
            for (int n = 0; n < 4; ++n) {
                float bvv = bf2f(*(const u16*)((const char*)mybl + q * 128 +
                                 (((n * 16 + h16) * 2) ^ ((q & 7) << 4))));
                float sv = sacc[n][r] * SCL2 + bvv;
                sacc[n][r] = sv; mx = fmaxf(mx, sv);
            }
            mx = fmaxf(mx, __shfl_xor(mx, 1)); mx = fmaxf(mx, __shfl_xor(mx, 2));
            mx = fmaxf(mx, __shfl_xor(mx, 4)); mx = fmaxf(mx, __shfl_xor(mx, 8));
            float mn = fmaxf(m0[r], mx);
            cr[r] = __builtin_amdgcn_exp2f(m0[r] - mn); m0[r] = mn;
            float sum = 0.f;
#pragma unroll
            for (int n = 0; n < 4; ++n) {
                float p = __builtin_amdgcn_exp2f(sacc[n][r] - mn); sacc[n][r] = p; sum += p;
            }
            sum += __shfl_xor(sum, 1); sum += __shfl_xor(sum, 2);
            sum += __shfl_xor(sum, 4); sum += __shfl_xor(sum, 8);
            l0[r] = l0[r] * cr[r] + sum;
        }
#pragma unroll
        for (int n = 0; n < 4; ++n)
#pragma unroll
            for (int r = 0; r < 4; ++r) {
                int q = g4 * 4 + r, c = n * 16 + h16;
                *(u16*)((char*)mypl + q * 128 + ((c * 2) ^ ((q & 7) << 4))) =
                    (u16)(__builtin_bit_cast(unsigned int, sacc[n][r]) >> 16);
            }
#pragma unroll
        for (int d = 0; d < 4; ++d) {
            f32x4 o = oacc[d];
            o[0] *= cr[0]; o[1] *= cr[1]; o[2] *= cr[2]; o[3] *= cr[3];
            oacc[d] = o;
        }
        short8 pf[2];
#pragma unroll
        for (int ks = 0; ks < 2; ++ks)
            pf[ks] = *(const short8*)((const char*)mypl + h16 * 128 + ((ks * 64 + g4 * 16) ^ ((h16 & 7) << 4)));
        __builtin_amdgcn_s_setprio(1);
#pragma unroll
        for (int d = 0; d < 4; ++d) {
            int row = d * 16 + h16, swzv = (row & 7) << 4;
#pragma unroll
            for (int ks = 0; ks < 2; ++ks) {
                short8 vf = *(const short8*)((const char*)vl + row * 128 + ((ks * 64 + g4 * 16) ^ swzv));
                oacc[d] = __builtin_amdgcn_mfma_f32_16x16x32_bf16(pf[ks], vf, oacc[d], 0, 0, 0);
            }
        }
        __builtin_amdgcn_s_setprio(0);
    }
    float* P = Part + ((((long)(b * H_ + hh) * 32 + qb * 4 + wid) * S + s) * 1088);
#pragma unroll
    for (int d = 0; d < 4; ++d)
#pragma unroll
        for (int r = 0; r < 4; ++r)
            P[(g4 * 4 + r) * 64 + d * 16 + h16] = oacc[d][r];
    if (h16 == 0) {
#pragma unroll
        for (int r = 0; r < 4; ++r) {
            P[1024 + g4 * 4 + r] = m0[r];
            P[1056 + g4 * 4 + r] = l0[r];
        }
    }
}

// combine S=4 partials -> bf16 output rows (exp2 domain)
__global__ __launch_bounds__(64) void fcomb(const float* __restrict__ Part, u16* __restrict__ Ob) {
    int q16 = blockIdx.x, hh = blockIdx.y, b = blockIdx.z, lane = threadIdx.x;
    const float* base = Part + (((long)(b * H_ + hh) * 32 + q16) * 4) * 1088;
#pragma unroll 4
    for (int q = 0; q < 16; ++q) {
        float m0 = base[1024 + q],        m1 = base[1088 + 1024 + q];
        float m2 = base[2176 + 1024 + q], m3 = base[3264 + 1024 + q];
        float M = fmaxf(fmaxf(m0, m1), fmaxf(m2, m3));
        float w0 = __builtin_amdgcn_exp2f(m0 - M), w1 = __builtin_amdgcn_exp2f(m1 - M);
        float w2 = __builtin_amdgcn_exp2f(m2 - M), w3 = __builtin_amdgcn_exp2f(m3 - M);
        float L = w0 * base[1056 + q] + w1 * base[1088 + 1056 + q] +
                  w2 * base[2176 + 1056 + q] + w3 * base[3264 + 1056 + q];
        float o = w0 * base[q * 64 + lane] + w1 * base[1088 + q * 64 + lane] +
                  w2 * base[2176 + q * 64 + lane] + w3 * base[3264 + q * 64 + lane];
        Ob[(long)(b * NQ_ + q16 * 16 + q) * D_ + hh * 64 + lane] = f2bf(o * (1.f / L));
    }
}

// ---------------- batched bf16 GEMM, B supplied transposed (N,K) ----------------
enum { EP_BIAS = 0, EP_SCALE = 1, EP_RES = 3, EP_GELU = 4 };

template <int BM, int BN, int EPI>
__global__ __launch_bounds__(256) void gemm_bt(
    const u16* __restrict__ A, const u16* __restrict__ B, void* __restrict__ Cv,
    const float* __restrict__ bias, const float* __restrict__ res,
    int M, int N, int K, int lda, int ldb, int ldc,
    int bdiv, long sAb, long sAh, long sBb, long sBh, long sCb, long sCh,
    float scale, int biasz) {
    constexpr int BK = 64;
    __shared__ u16 lA[BM * BK];
    __shared__ u16 lB[BN * BK];
    const int z = blockIdx.z;
    const int zb = z / bdiv, zh = z % bdiv;
    const u16* Ab = A + zb * sAb + zh * sAh;
    const u16* Bb = B + zb * sBb + zh * sBh;
    const int bm = blockIdx.y * BM;
    const int bn = blockIdx.x * BN;
    const int tid = threadIdx.x;
    const int lane = tid & 63, wid = tid >> 6;
    const int wm = (wid >> 1) * (BM / 2);
    const int wn = (wid & 1) * (BN / 2);
    constexpr int FM = BM / 32, FN = BN / 32;
    f32x4 acc[FM][FN] = {};
    const int lrow = lane & 15, lk = (lane >> 4) * 8;

    for (int kb = 0; kb < K; kb += BK) {
#pragma unroll
        for (int i = 0; i < (BM * 8) / 256; ++i) {
            int ch = tid + i * 256;
            int r = ch >> 3, c = ch & 7;
            gload_lds16(Ab + (long)(bm + r) * lda + kb + c * 8, lA + ch * 8);
        }
#pragma unroll
        for (int i = 0; i < (BN * 8) / 256; ++i) {
            int ch = tid + i * 256;
            int r = ch >> 3, c = ch & 7;
            gload_lds16(Bb + (long)(bn + r) * ldb + kb + c * 8, lB + ch * 8);
        }
        __syncthreads();
#pragma unroll
        for (int ks = 0; ks < 2; ++ks) {
            short8 af[FM], bfr[FN];
#pragma unroll
            for (int i = 0; i < FM; ++i)
                af[i] = *(const short8*)(lA + (wm + i * 16 + lrow) * BK + ks * 32 + lk);
#pragma unroll
            for (int j = 0; j < FN; ++j)
                bfr[j] = *(const short8*)(lB + (wn + j * 16 + lrow) * BK + ks * 32 + lk);
#pragma unroll
            for (int i = 0; i < FM; ++i)
#pragma unroll
                for (int j = 0; j < FN; ++j)
                    acc[i][j] = __builtin_amdgcn_mfma_f32_16x16x32_bf16(af[i], bfr[j], acc[i][j], 0, 0, 0);
        }
        __syncthreads();
    }

    long coff = zb * sCb + zh * sCh;
#pragma unroll
    for (int i = 0; i < FM; ++i) {
#pragma unroll
        for (int j = 0; j < FN; ++j) {
#pragma unroll
            for (int r = 0; r < 4; ++r) {
                int row = bm + wm + i * 16 + (lane >> 4) * 4 + r;
                int col = bn + wn + j * 16 + (lane & 15);
                long idx = coff + (long)row * ldc + col;
                float v = acc[i][j][r];
                if (EPI == EP_SCALE) {
                    ((u16*)Cv)[idx] = f2bf(v * scale);
                } else if (EPI == EP_RES) {
                    float tt = v + (bias ? bias[col] : 0.f);
                    ((float*)Cv)[idx] = res[idx] + tt;
                } else if (EPI == EP_GELU) {
                    float tt = v + (bias ? bias[col] : 0.f);
                    ((u16*)Cv)[idx] = f2bf(gelu_f(tt));
                } else {
                    float tt = v + (bias ? bias[biasz * zb + col] : 0.f);
                    ((u16*)Cv)[idx] = f2bf(tt);
                }
            }
        }
    }
}

extern "C" void kernel_launch(void* const* d_in, const int* in_sizes, int n_in,
                              void* d_out, int out_size, void* d_ws, size_t ws_size,
                              hipStream_t stream) {
    const float* x_in   = (const float*)d_in[0];
    const float* ctx_k  = (const float*)d_in[1];
    const float* ctx_v  = (const float*)d_in[2];
    const float* qcoord = (const float*)d_in[3];
    const float* ccoord = (const float*)d_in[4];
    const float* sn_g   = (const float*)d_in[5];
    const float* sn_b   = (const float*)d_in[6];
    const float* wqkv   = (const float*)d_in[7];
    const float* bqkv   = (const float*)d_in[8];
    const float* wo_s   = (const float*)d_in[9];
    const float* bo_s   = (const float*)d_in[10];
    const float* cn_g   = (const float*)d_in[11];
    const float* cn_b   = (const float*)d_in[12];
    const float* wq     = (const float*)d_in[13];
    const float* bq     = (const float*)d_in[14];
    const float* wk     = (const float*)d_in[15];
    const float* bk     = (const float*)d_in[16];
    const float* wv     = (const float*)d_in[17];
    const float* bv     = (const float*)d_in[18];
    const float* wo_c   = (const float*)d_in[19];
    const float* bo_c   = (const float*)d_in[20];
    const float* rb_w1  = (const float*)d_in[21];
    const float* rb_b1  = (const float*)d_in[22];
    const float* rb_w2  = (const float*)d_in[23];
    const float* rb_b2  = (const float*)d_in[24];
    const float* fn_g   = (const float*)d_in[25];
    const float* fn_b   = (const float*)d_in[26];
    const float* fw1    = (const float*)d_in[27];
    const float* fb1    = (const float*)d_in[28];
    const float* fw2    = (const float*)d_in[29];
    const float* fb2    = (const float*)d_in[30];

    char* ws = (char*)d_ws;
    size_t off = 0;
    auto alloc = [&](size_t bytes) -> void* {
        void* p = ws + off; off += (bytes + 255) & ~(size_t)255; return p;
    };
    u16* wT_qkv = (u16*)alloc((size_t)2304 * 768 * 2);
    u16* wT_os  = (u16*)alloc((size_t)768 * 768 * 2);
    u16* wT_q   = (u16*)alloc((size_t)768 * 768 * 2);
    u16* wT_k   = (u16*)alloc((size_t)768 * 768 * 2);   // adjacent to wT_v (sBb)
    u16* wT_v   = (u16*)alloc((size_t)768 * 768 * 2);
    u16* wT_oc  = (u16*)alloc((size_t)768 * 768 * 2);
    u16* wT_f1  = (u16*)alloc((size_t)3072 * 768 * 2);
    u16* wT_f2  = (u16*)alloc((size_t)768 * 3072 * 2);
    u16* ckb    = (u16*)alloc((size_t)B_ * NC_ * D_ * 2);  // adjacent to cvb (sAb)
    u16* cvb    = (u16*)alloc((size_t)B_ * NC_ * D_ * 2);
    u16* xln    = (u16*)alloc((size_t)1024 * 768 * 2);
    u16* qkv    = (u16*)alloc((size_t)1024 * 2304 * 2);
    u16* vts    = (u16*)alloc((size_t)24 * 64 * 512 * 2);
    u16* oatt   = (u16*)alloc((size_t)1024 * 768 * 2);
    float* x1   = (float*)alloc((size_t)1024 * 768 * 4);
    u16* xln2   = (u16*)alloc((size_t)1024 * 768 * 2);
    u16* qc     = (u16*)alloc((size_t)1024 * 768 * 2);
    u16* kc     = (u16*)alloc((size_t)4096 * 768 * 2);  // adjacent to vc (sCb)
    u16* vc     = (u16*)alloc((size_t)4096 * 768 * 2);
    u16* clog   = (u16*)alloc((size_t)24 * 512 * 2048 * 2);
    u16* vtc    = (u16*)alloc((size_t)24 * 64 * 2048 * 2);
    u16* oc2    = (u16*)alloc((size_t)1024 * 768 * 2);
    float* x2   = (float*)alloc((size_t)1024 * 768 * 4);
    u16* xln3   = (u16*)alloc((size_t)1024 * 768 * 2);
    u16* ffh    = (u16*)alloc((size_t)1024 * 3072 * 2);
    float* part = (float*)alloc((size_t)2 * H_ * 32 * 4 * 1088 * 4);
    float* bkv  = (float*)alloc((size_t)1536 * 4);
    (void)ws_size; (void)in_sizes; (void)n_in; (void)out_size;

    // merged prep: all transposes + context bf16 convert + bias concat
    prep<<<15366, 256, 0, stream>>>(wqkv, wT_qkv, wo_s, wq, wk, wv, wo_c,
                                    wT_os, wT_q, wT_k, wT_v, wT_oc,
                                    fw1, wT_f1, fw2, wT_f2,
                                    ctx_k, ckb, ctx_v, cvb, bk, bv, bkv);

    // ---- self attention ----
    ln_k<<<1024, 256, 0, stream>>>(x_in, sn_g, sn_b, xln);
    gemm_bt<32, 64, EP_BIAS><<<dim3(2304 / 64, 1024 / 32, 1), 256, 0, stream>>>(
        xln, wT_qkv, qkv, bqkv, nullptr, 1024, 2304, 768, 768, 768, 2304,
        1, 0, 0, 0, 0, 0, 0, 1.f, 0);
    bias_mlp7<<<dim3(NC_ / 256, NQ_ / 4, B_), 256, 0, stream>>>(qcoord, ccoord, rb_w1, rb_b1, rb_w2, rb_b2, clog);
    vtrans<<<dim3(512 / 32, 2, 24), 256, 0, stream>>>(qkv + 1536, vts, 512, 2304, 12, (long)512 * 2304, 64);
    fattn<512, false><<<dim3(NQ_ / 16, H_, B_), 64, 0, stream>>>(
        qkv, qkv + 768, vts, nullptr, oatt, 2304, 2304);
    gemm_bt<32, 64, EP_RES><<<dim3(768 / 64, 1024 / 32, 1), 256, 0, stream>>>(
        oatt, wT_os, x1, bo_s, x_in, 1024, 768, 768, 768, 768, 768,
        1, 0, 0, 0, 0, 0, 0, 1.f, 0);

    // ---- cross attention ----
    ln_k<<<1024, 256, 0, stream>>>(x1, cn_g, cn_b, xln2);
    gemm_bt<32, 64, EP_BIAS><<<dim3(768 / 64, 1024 / 32, 1), 256, 0, stream>>>(
        xln2, wT_q, qc, bq, nullptr, 1024, 768, 768, 768, 768, 768,
        1, 0, 0, 0, 0, 0, 0, 1.f, 0);
    // merged K-proj (z=0) + V-proj (z=1)
    gemm_bt<64, 128, EP_BIAS><<<dim3(768 / 128, 4096 / 64, 2), 256, 0, stream>>>(
        ckb, wT_k, kc, bkv, nullptr, 4096, 768, 768, 768, 768, 768,
        1, (long)B_ * NC_ * D_, 0, (long)768 * 768, 0, (long)4096 * 768, 0, 1.f, 768);
    vtrans<<<dim3(2048 / 32, 2, 24), 256, 0, stream>>>(vc, vtc, 2048, 768, 12, (long)2048 * 768, 64);
    fattn4<8, 4><<<dim3(8, H_, B_ * 4), 256, 0, stream>>>(
        qc, kc, vtc, clog, part, 768, 768, 2048, 2048);
    fcomb<<<dim3(32, H_, B_), 64, 0, stream>>>(part, oc2);
    gemm_bt<32, 64, EP_RES><<<dim3(768 / 64, 1024 / 32, 1), 256, 0, stream>>>(
        oc2, wT_oc, x2, bo_c, x1, 1024, 768, 768, 768, 768, 768,
        1, 0, 0, 0, 0, 0, 0, 1.f, 0);

    // ---- FFN ----
    ln_k<<<1024, 256, 0, stream>>>(x2, fn_g, fn_b, xln3);
    gemm_bt<32, 64, EP_GELU><<<dim3(3072 / 64, 1024 / 32, 1), 256, 0, stream>>>(
        xln3, wT_f1, ffh, fb1, nullptr, 1024, 3072, 768, 768, 768, 3072,
        1, 0, 0, 0, 0, 0, 0, 1.f, 0);
    gemm_bt<32, 64, EP_RES><<<dim3(768 / 64, 1024 / 32, 1), 256, 0, stream>>>(
        ffh, wT_f2, (float*)d_out, fb2, x2, 1024, 768, 3072, 3072, 3072, 768,
        1, 0, 0, 0, 0, 0, 0, 1.f, 0);
}